// Round 13
// baseline (540.364 us; speedup 1.0000x reference)
//
#include <hip/hip_runtime.h>
#include <hip/hip_bf16.h>
#include <hip/hip_fp16.h>

#define NEG_SLOPE 0.2f
#define LOG2E 1.4426950408889634f

typedef _Float16 h2v __attribute__((ext_vector_type(2)));

// ------------------------------------------------------------ CSR build
__global__ void deg_count_k(const int* __restrict__ dstA, int* __restrict__ deg, int E) {
  int e = blockIdx.x * blockDim.x + threadIdx.x;
  if (e < E) atomicAdd(&deg[dstA[e]], 1);
}

// exclusive scan, 3 phases (N <= 512*256)
__global__ void scan1_k(const int* __restrict__ deg, int* __restrict__ rowptr,
                        int* __restrict__ aux, int N) {
  __shared__ int sh[256];
  int t = threadIdx.x, i = blockIdx.x * 256 + t;
  int v = (i < N) ? deg[i] : 0;
  sh[t] = v; __syncthreads();
  for (int off = 1; off < 256; off <<= 1) {
    int x = (t >= off) ? sh[t - off] : 0;
    __syncthreads();
    sh[t] += x;
    __syncthreads();
  }
  if (i < N) rowptr[i] = sh[t] - v;
  if (t == 255) aux[blockIdx.x] = sh[255];
}

__global__ void scan2_k(int* __restrict__ aux, int naux) {
  __shared__ int sh[512];
  int t = threadIdx.x;
  int v = (t < naux) ? aux[t] : 0;
  sh[t] = v; __syncthreads();
  for (int off = 1; off < 512; off <<= 1) {
    int x = (t >= off) ? sh[t - off] : 0;
    __syncthreads();
    sh[t] += x;
    __syncthreads();
  }
  if (t < naux) aux[t] = sh[t] - v;
}

__global__ void scan3_k(int* __restrict__ rowptr, int* __restrict__ cursor,
                        const int* __restrict__ aux, int N, int E) {
  int i = blockIdx.x * blockDim.x + threadIdx.x;
  if (i < N) {
    int r = rowptr[i] + aux[i >> 8];
    rowptr[i] = r;
    cursor[i] = r;
  } else if (i == N) {
    rowptr[N] = E;
  }
}

// scatter: builds csr_src AND permuted fp16 edge-attrs (CSR order, 32B/edge)
__global__ void scatter_k(const int* __restrict__ srcA, const int* __restrict__ dstA,
                          const float* __restrict__ ea, int* __restrict__ cursor,
                          int* __restrict__ csr_src, uint4* __restrict__ ea_h, int E) {
  int e = blockIdx.x * blockDim.x + threadIdx.x;
  if (e >= E) return;
  int pos = atomicAdd(&cursor[dstA[e]], 1);
  csr_src[pos] = srcA[e];
  const float* p = ea + (size_t)e * 16;
  union { __half2 h2[8]; uint4 u[2]; } cv;
#pragma unroll
  for (int k = 0; k < 8; ++k) cv.h2[k] = __floats2half2_rn(p[2 * k], p[2 * k + 1]);
  uint4* d = ea_h + (size_t)pos * 2;
  d[0] = cv.u[0];
  d[1] = cv.u[1];
}

// ------------------------------------------------- layer1 node transform (128 -> 64|64)
__global__ __launch_bounds__(256) void transform1_k(
    const float* __restrict__ x, const float* __restrict__ wl, const float* __restrict__ wr,
    float* __restrict__ xl, float* __restrict__ xr, int N) {
  __shared__ float wS[128 * 128];
  __shared__ float xs[32 * 128];
  int t = threadIdx.x;
  for (int i = t; i < 128 * 64; i += 256) {
    int k = i >> 6, j = i & 63;
    wS[k * 128 + j]      = wl[i];
    wS[k * 128 + 64 + j] = wr[i];
  }
  __syncthreads();
  int tc = t & 31;
  int tr = t >> 5;
  int ntiles = (N + 31) >> 5;
  for (int tile = blockIdx.x; tile < ntiles; tile += gridDim.x) {
    int base = tile << 5;
    const float4* x4 = (const float4*)x;
    float4* xs4 = (float4*)xs;
    for (int i = t; i < 1024; i += 256) {
      int node = base + (i >> 5);
      float4 v = {0.f, 0.f, 0.f, 0.f};
      if (node < N) v = x4[(size_t)node * 32 + (i & 31)];
      xs4[i] = v;
    }
    __syncthreads();
    float4 acc0 = {0,0,0,0}, acc1 = {0,0,0,0}, acc2 = {0,0,0,0}, acc3 = {0,0,0,0};
    const float* xrow = &xs[tr * 4 * 128];
#pragma unroll 4
    for (int k = 0; k < 128; ++k) {
      float4 w4 = *(const float4*)&wS[k * 128 + tc * 4];
      float x0 = xrow[k], x1 = xrow[128 + k], x2 = xrow[256 + k], x3 = xrow[384 + k];
      acc0.x += x0 * w4.x; acc0.y += x0 * w4.y; acc0.z += x0 * w4.z; acc0.w += x0 * w4.w;
      acc1.x += x1 * w4.x; acc1.y += x1 * w4.y; acc1.z += x1 * w4.z; acc1.w += x1 * w4.w;
      acc2.x += x2 * w4.x; acc2.y += x2 * w4.y; acc2.z += x2 * w4.z; acc2.w += x2 * w4.w;
      acc3.x += x3 * w4.x; acc3.y += x3 * w4.y; acc3.z += x3 * w4.z; acc3.w += x3 * w4.w;
    }
    float* dp = (tc < 16) ? xl : xr;
    int j4 = (tc & 15) * 4;
    int nb = base + tr * 4;
    if (nb + 0 < N) *(float4*)&dp[(size_t)(nb + 0) * 64 + j4] = acc0;
    if (nb + 1 < N) *(float4*)&dp[(size_t)(nb + 1) * 64 + j4] = acc1;
    if (nb + 2 < N) *(float4*)&dp[(size_t)(nb + 2) * 64 + j4] = acc2;
    if (nb + 3 < N) *(float4*)&dp[(size_t)(nb + 3) * 64 + j4] = acc3;
    __syncthreads();
  }
}

// ------------------------------------------------- layer2 node transform (64 -> 32|32)
__global__ __launch_bounds__(256) void transform2_k(
    const float* __restrict__ h, const float* __restrict__ wl, const float* __restrict__ wr,
    float* __restrict__ xl, float* __restrict__ xr, int N) {
  __shared__ float wS[64 * 64];
  __shared__ float xs[64 * 64];
  int t = threadIdx.x;
  for (int i = t; i < 64 * 32; i += 256) {
    int k = i >> 5, j = i & 31;
    wS[k * 64 + j]      = wl[i];
    wS[k * 64 + 32 + j] = wr[i];
  }
  __syncthreads();
  int tc = t & 15;
  int tr = t >> 4;
  int ntiles = (N + 63) >> 6;
  for (int tile = blockIdx.x; tile < ntiles; tile += gridDim.x) {
    int base = tile << 6;
    const float4* h4 = (const float4*)h;
    float4* xs4 = (float4*)xs;
    for (int i = t; i < 1024; i += 256) {
      int node = base + (i >> 4);
      float4 v = {0.f, 0.f, 0.f, 0.f};
      if (node < N) v = h4[(size_t)node * 16 + (i & 15)];
      xs4[i] = v;
    }
    __syncthreads();
    float4 acc0 = {0,0,0,0}, acc1 = {0,0,0,0}, acc2 = {0,0,0,0}, acc3 = {0,0,0,0};
    const float* xrow = &xs[tr * 4 * 64];
#pragma unroll 4
    for (int k = 0; k < 64; ++k) {
      float4 w4 = *(const float4*)&wS[k * 64 + tc * 4];
      float x0 = xrow[k], x1 = xrow[64 + k], x2 = xrow[128 + k], x3 = xrow[192 + k];
      acc0.x += x0 * w4.x; acc0.y += x0 * w4.y; acc0.z += x0 * w4.z; acc0.w += x0 * w4.w;
      acc1.x += x1 * w4.x; acc1.y += x1 * w4.y; acc1.z += x1 * w4.z; acc1.w += x1 * w4.w;
      acc2.x += x2 * w4.x; acc2.y += x2 * w4.y; acc2.z += x2 * w4.z; acc2.w += x2 * w4.w;
      acc3.x += x3 * w4.x; acc3.y += x3 * w4.y; acc3.z += x3 * w4.z; acc3.w += x3 * w4.w;
    }
    float* dp = (tc < 8) ? xl : xr;
    int j4 = (tc & 7) * 4;
    int nb = base + tr * 4;
    if (nb + 0 < N) *(float4*)&dp[(size_t)(nb + 0) * 32 + j4] = acc0;
    if (nb + 1 < N) *(float4*)&dp[(size_t)(nb + 1) * 32 + j4] = acc1;
    if (nb + 2 < N) *(float4*)&dp[(size_t)(nb + 2) * 32 + j4] = acc2;
    if (nb + 3 < N) *(float4*)&dp[(size_t)(nb + 3) * 32 + j4] = acc3;
    __syncthreads();
  }
}

// ------------------------------------------------- GAT layer1: one wave per node (pull)
// readlane -> SGPR src index -> scalar-base gathers; fmax leaky; exp2 basis.
__global__ __launch_bounds__(256) void gat1_k(
    const int* __restrict__ rowptr, const int* __restrict__ csr_src,
    const uint4* __restrict__ ea_h, const float* __restrict__ we,
    const float* __restrict__ att, const float* __restrict__ b,
    const float* __restrict__ xl, const float* __restrict__ xr,
    float* __restrict__ h, int N) {
  int t = threadIdx.x;
  int lane = t & 63;
  h2v wh[8];
#pragma unroll
  for (int k = 0; k < 8; ++k) {
    wh[k].x = (_Float16)we[(2 * k) * 64 + lane];
    wh[k].y = (_Float16)we[(2 * k + 1) * 64 + lane];
  }
  float att_r = att[lane] * LOG2E;
  float b_r = b[lane];
  int wid = (blockIdx.x * blockDim.x + t) >> 6;
  int n0 = wid * 4;
  for (int jj = 0; jj < 4; ++jj) {
    int n = n0 + jj;
    if (n >= N) break;
    float xr_v = xr[(size_t)n * 64 + lane];
    float xl_s = xl[(size_t)n * 64 + lane];
    float num = 0.f, den = 0.f, efsum = 0.f;
    int rs = __builtin_amdgcn_readfirstlane(rowptr[n]);
    int re = __builtin_amdgcn_readfirstlane(rowptr[n + 1]);
    for (int base = rs; base < re; base += 64) {
      int cnt = min(64, re - base);
      int s_l = 0;
      if (lane < cnt) s_l = csr_src[base + lane];
      int i = 0;
      for (; i + 1 < cnt; i += 2) {
        int sa = __builtin_amdgcn_readlane(s_l, i);
        int sb = __builtin_amdgcn_readlane(s_l, i + 1);
        const float* pa = xl + (size_t)sa * 64;
        const float* pb = xl + (size_t)sb * 64;
        float xa = pa[lane];
        float xb = pb[lane];
        const uint4* epa = ea_h + (size_t)(base + i) * 2;
        union { uint4 u; h2v h[4]; } a0, a1, c0, c1;
        a0.u = epa[0]; a1.u = epa[1];
        c0.u = epa[2]; c1.u = epa[3];        // edge i+1 contiguous
        float fa0 = 0.f, fa1 = 0.f, fb0 = 0.f, fb1 = 0.f;
        fa0 = __builtin_amdgcn_fdot2(a0.h[0], wh[0], fa0, false);
        fb0 = __builtin_amdgcn_fdot2(c0.h[0], wh[0], fb0, false);
        fa1 = __builtin_amdgcn_fdot2(a0.h[1], wh[1], fa1, false);
        fb1 = __builtin_amdgcn_fdot2(c0.h[1], wh[1], fb1, false);
        fa0 = __builtin_amdgcn_fdot2(a0.h[2], wh[2], fa0, false);
        fb0 = __builtin_amdgcn_fdot2(c0.h[2], wh[2], fb0, false);
        fa1 = __builtin_amdgcn_fdot2(a0.h[3], wh[3], fa1, false);
        fb1 = __builtin_amdgcn_fdot2(c0.h[3], wh[3], fb1, false);
        fa0 = __builtin_amdgcn_fdot2(a1.h[0], wh[4], fa0, false);
        fb0 = __builtin_amdgcn_fdot2(c1.h[0], wh[4], fb0, false);
        fa1 = __builtin_amdgcn_fdot2(a1.h[1], wh[5], fa1, false);
        fb1 = __builtin_amdgcn_fdot2(c1.h[1], wh[5], fb1, false);
        fa0 = __builtin_amdgcn_fdot2(a1.h[2], wh[6], fa0, false);
        fb0 = __builtin_amdgcn_fdot2(c1.h[2], wh[6], fb0, false);
        fa1 = __builtin_amdgcn_fdot2(a1.h[3], wh[7], fa1, false);
        fb1 = __builtin_amdgcn_fdot2(c1.h[3], wh[7], fb1, false);
        float fa = fa0 + fa1, fb = fb0 + fb1;
        float ma = xa + xr_v + fa; ma = fmaxf(ma, NEG_SLOPE * ma);
        float mb = xb + xr_v + fb; mb = fmaxf(mb, NEG_SLOPE * mb);
        float ta = ma * att_r, tb = mb * att_r;
#pragma unroll
        for (int off = 1; off < 32; off <<= 1) {
          ta += __shfl_xor(ta, off);
          tb += __shfl_xor(tb, off);
        }
        float ga = exp2f(ta), gb = exp2f(tb);
        num += ga * xa + gb * xb;
        den += ga + gb;
        efsum += fa + fb;
      }
      if (i < cnt) {                          // single tail edge, unmasked
        int sa = __builtin_amdgcn_readlane(s_l, i);
        const float* pa = xl + (size_t)sa * 64;
        float xa = pa[lane];
        const uint4* epa = ea_h + (size_t)(base + i) * 2;
        union { uint4 u; h2v h[4]; } a0, a1;
        a0.u = epa[0]; a1.u = epa[1];
        float fa0 = 0.f, fa1 = 0.f;
        fa0 = __builtin_amdgcn_fdot2(a0.h[0], wh[0], fa0, false);
        fa1 = __builtin_amdgcn_fdot2(a0.h[1], wh[1], fa1, false);
        fa0 = __builtin_amdgcn_fdot2(a0.h[2], wh[2], fa0, false);
        fa1 = __builtin_amdgcn_fdot2(a0.h[3], wh[3], fa1, false);
        fa0 = __builtin_amdgcn_fdot2(a1.h[0], wh[4], fa0, false);
        fa1 = __builtin_amdgcn_fdot2(a1.h[1], wh[5], fa1, false);
        fa0 = __builtin_amdgcn_fdot2(a1.h[2], wh[6], fa0, false);
        fa1 = __builtin_amdgcn_fdot2(a1.h[3], wh[7], fa1, false);
        float fa = fa0 + fa1;
        float ma = xa + xr_v + fa; ma = fmaxf(ma, NEG_SLOPE * ma);
        float ta = ma * att_r;
#pragma unroll
        for (int off = 1; off < 32; off <<= 1) ta += __shfl_xor(ta, off);
        float ga = exp2f(ta);
        num += ga * xa;
        den += ga;
        efsum += fa;
      }
    }
    // self loop: ef_self = mean(ea@we) = efsum/deg
    int deg = re - rs;
    float ef_self = efsum / fmaxf((float)deg, 1.f);
    float mm = xl_s + xr_v + ef_self;
    mm = fmaxf(mm, NEG_SLOPE * mm);
    float s2 = mm * att_r;
#pragma unroll
    for (int off = 1; off < 32; off <<= 1) s2 += __shfl_xor(s2, off);
    float e2 = exp2f(s2);
    num += e2 * xl_s;
    den += e2;
    h[(size_t)n * 64 + lane] = fmaxf(num / fmaxf(den, 1e-16f) + b_r, 0.f);
  }
}

// ------------------------------------------------- GAT layer2: one wave per node
// Half-waves process edge i (par=0) / i+1 (par=1) of the SAME node -> uniform
// control flow, readlane src indices, cross-half merge at node end.
__global__ __launch_bounds__(256) void gat2_k(
    const int* __restrict__ rowptr, const int* __restrict__ csr_src,
    const uint4* __restrict__ ea_h, const float* __restrict__ we,
    const float* __restrict__ att, const float* __restrict__ b,
    const float* __restrict__ xl, const float* __restrict__ xr,
    float* __restrict__ h, int N) {
  int t = threadIdx.x;
  int lane = t & 63;
  int c = lane & 31;
  int par = lane >> 5;                 // 0: edge i, 1: edge i+1
  h2v wh[8];
#pragma unroll
  for (int k = 0; k < 8; ++k) {
    wh[k].x = (_Float16)we[(2 * k) * 32 + c];
    wh[k].y = (_Float16)we[(2 * k + 1) * 32 + c];
  }
  float att_r = att[c] * LOG2E;
  float b_r = b[c];
  int wid = (blockIdx.x * blockDim.x + t) >> 6;
  int n0 = wid * 4;
  for (int jj = 0; jj < 4; ++jj) {
    int n = n0 + jj;
    if (n >= N) break;
    float xr_v = xr[(size_t)n * 32 + c];
    float xl_s = xl[(size_t)n * 32 + c];
    float num = 0.f, den = 0.f, efsum = 0.f;
    int rs = __builtin_amdgcn_readfirstlane(rowptr[n]);
    int re = __builtin_amdgcn_readfirstlane(rowptr[n + 1]);
    for (int base = rs; base < re; base += 64) {
      int cnt = min(64, re - base);
      int s_l = 0;
      if (lane < cnt) s_l = csr_src[base + lane];
      int i = 0;
      for (; i + 1 < cnt; i += 2) {
        int sa0 = __builtin_amdgcn_readlane(s_l, i);
        int sa1 = __builtin_amdgcn_readlane(s_l, i + 1);
        int sa = par ? sa1 : sa0;
        const float* p = xl + (size_t)sa * 32;
        float xa = p[c];
        const uint4* ep = ea_h + (size_t)(base + i + par) * 2;
        union { uint4 u; h2v h[4]; } a0, a1;
        a0.u = ep[0]; a1.u = ep[1];
        float fa0 = 0.f, fa1 = 0.f;
        fa0 = __builtin_amdgcn_fdot2(a0.h[0], wh[0], fa0, false);
        fa1 = __builtin_amdgcn_fdot2(a0.h[1], wh[1], fa1, false);
        fa0 = __builtin_amdgcn_fdot2(a0.h[2], wh[2], fa0, false);
        fa1 = __builtin_amdgcn_fdot2(a0.h[3], wh[3], fa1, false);
        fa0 = __builtin_amdgcn_fdot2(a1.h[0], wh[4], fa0, false);
        fa1 = __builtin_amdgcn_fdot2(a1.h[1], wh[5], fa1, false);
        fa0 = __builtin_amdgcn_fdot2(a1.h[2], wh[6], fa0, false);
        fa1 = __builtin_amdgcn_fdot2(a1.h[3], wh[7], fa1, false);
        float fa = fa0 + fa1;
        float ma = xa + xr_v + fa; ma = fmaxf(ma, NEG_SLOPE * ma);
        float ta = ma * att_r;
#pragma unroll
        for (int off = 1; off < 32; off <<= 1) ta += __shfl_xor(ta, off);
        float ga = exp2f(ta);
        num += ga * xa;
        den += ga;
        efsum += fa;
      }
      if (i < cnt) {                        // odd tail: half 0 only
        if (par == 0) {
          int sa = __builtin_amdgcn_readlane(s_l, i);
          const float* p = xl + (size_t)sa * 32;
          float xa = p[c];
          const uint4* ep = ea_h + (size_t)(base + i) * 2;
          union { uint4 u; h2v h[4]; } a0, a1;
          a0.u = ep[0]; a1.u = ep[1];
          float fa0 = 0.f, fa1 = 0.f;
          fa0 = __builtin_amdgcn_fdot2(a0.h[0], wh[0], fa0, false);
          fa1 = __builtin_amdgcn_fdot2(a0.h[1], wh[1], fa1, false);
          fa0 = __builtin_amdgcn_fdot2(a0.h[2], wh[2], fa0, false);
          fa1 = __builtin_amdgcn_fdot2(a0.h[3], wh[3], fa1, false);
          fa0 = __builtin_amdgcn_fdot2(a1.h[0], wh[4], fa0, false);
          fa1 = __builtin_amdgcn_fdot2(a1.h[1], wh[5], fa1, false);
          fa0 = __builtin_amdgcn_fdot2(a1.h[2], wh[6], fa0, false);
          fa1 = __builtin_amdgcn_fdot2(a1.h[3], wh[7], fa1, false);
          float fa = fa0 + fa1;
          float ma = xa + xr_v + fa; ma = fmaxf(ma, NEG_SLOPE * ma);
          float ta = ma * att_r;
#pragma unroll
          for (int off = 1; off < 32; off <<= 1) ta += __shfl_xor(ta, off);
          float ga = exp2f(ta);
          num += ga * xa;
          den += ga;
          efsum += fa;
        }
      }
    }
    // merge halves
    num += __shfl_xor(num, 32);
    den += __shfl_xor(den, 32);
    efsum += __shfl_xor(efsum, 32);
    // self loop
    int deg = re - rs;
    float ef_self = efsum / fmaxf((float)deg, 1.f);
    float mm = xl_s + xr_v + ef_self;
    mm = fmaxf(mm, NEG_SLOPE * mm);
    float s2 = mm * att_r;
#pragma unroll
    for (int off = 1; off < 32; off <<= 1) s2 += __shfl_xor(s2, off);
    float e2 = exp2f(s2);
    num += e2 * xl_s;
    den += e2;
    if (par == 0) h[(size_t)n * 32 + c] = fmaxf(num / fmaxf(den, 1e-16f) + b_r, 0.f);
  }
}

// ------------------------------------------------- fused mean-pool + fc
__global__ __launch_bounds__(256) void pool_fc_k(
    const float* __restrict__ h, const int* __restrict__ batch,
    const float* __restrict__ wfc, const float* __restrict__ bfc,
    float* __restrict__ out, int N) {
  int g = blockIdx.x;
  __shared__ int srange[2];
  __shared__ float part[8][32];
  int t = threadIdx.x;
  if (t < 2) {
    int key = g + t;
    int lo = 0, hi = N;
    while (lo < hi) { int mid = (lo + hi) >> 1; if (batch[mid] < key) lo = mid + 1; else hi = mid; }
    srange[t] = lo;
  }
  __syncthreads();
  int rs = srange[0], re = srange[1];
  int c = t & 31, sub = t >> 5;
  float acc = 0.f;
  for (int n = rs + sub; n < re; n += 8) acc += h[(size_t)n * 32 + c];
  part[sub][c] = acc;
  __syncthreads();
  if (sub == 0) {
    float s = part[0][c];
#pragma unroll
    for (int i = 1; i < 8; ++i) s += part[i][c];
    part[0][c] = s / fmaxf((float)(re - rs), 1.f);
  }
  __syncthreads();
  if (sub == 0) {
    float a = 0.f;
#pragma unroll
    for (int k = 0; k < 32; ++k) a += part[0][k] * wfc[k * 32 + c];
    out[g * 32 + c] = a + bfc[c];
  }
}

// ----------------------------------------------------------------- launcher
extern "C" void kernel_launch(void* const* d_in, const int* in_sizes, int n_in,
                              void* d_out, int out_size, void* d_ws, size_t ws_size,
                              hipStream_t stream) {
  const float* x   = (const float*)d_in[0];
  const int*   ei  = (const int*)d_in[1];
  const float* ea  = (const float*)d_in[2];
  const int*   bat = (const int*)d_in[3];
  const float* wl1 = (const float*)d_in[4];
  const float* wr1 = (const float*)d_in[5];
  const float* we1 = (const float*)d_in[6];
  const float* at1 = (const float*)d_in[7];
  const float* b1  = (const float*)d_in[8];
  const float* wl2 = (const float*)d_in[9];
  const float* wr2 = (const float*)d_in[10];
  const float* we2 = (const float*)d_in[11];
  const float* at2 = (const float*)d_in[12];
  const float* b2  = (const float*)d_in[13];
  const float* wfc = (const float*)d_in[14];
  const float* bfc = (const float*)d_in[15];

  const int N = in_sizes[0] / 128;
  const int E = in_sizes[1] / 2;
  const int G = 256;
  const int* srcA = ei;
  const int* dstA = ei + E;

  // ---- workspace layout (~110 MB) ----
  uint4* ea_h   = (uint4*)d_ws;                      // E*2 uint4 (fp16 attrs)
  float* xl1    = (float*)(ea_h + (size_t)E * 2);    // N*64
  float* xr1    = xl1 + (size_t)N * 64;              // N*64
  int*   deg    = (int*)(xr1 + (size_t)N * 64);      // N
  int*   rowptr = deg + N;                           // N+1
  int*   cursor = rowptr + (N + 1);                  // N
  int*   aux    = cursor + N;                        // 512
  int*   csr_src= aux + 512;                         // E
  float* h1     = xr1;                               // in-place over xr1
  float* xl2    = xl1;                               // N*32
  float* xr2    = xl1 + (size_t)N * 32;              // N*32
  float* h2     = xr2;                               // in-place over xr2

  const int naux = (N + 255) / 256;

  // ---- CSR build + ea permute ----
  hipMemsetAsync(deg, 0, (size_t)N * sizeof(int), stream);
  deg_count_k<<<(E + 255) / 256, 256, 0, stream>>>(dstA, deg, E);
  scan1_k<<<naux, 256, 0, stream>>>(deg, rowptr, aux, N);
  scan2_k<<<1, 512, 0, stream>>>(aux, naux);
  scan3_k<<<(N + 256) / 256, 256, 0, stream>>>(rowptr, cursor, aux, N, E);
  scatter_k<<<(E + 255) / 256, 256, 0, stream>>>(srcA, dstA, ea, cursor, csr_src, ea_h, E);

  // ---- layer 1 ----
  transform1_k<<<(N + 31) / 32, 256, 0, stream>>>(x, wl1, wr1, xl1, xr1, N);
  {
    int blocks1 = (N + 15) / 16;               // 4 waves/block * 4 nodes/wave
    gat1_k<<<blocks1, 256, 0, stream>>>(rowptr, csr_src, ea_h, we1, at1, b1,
                                        xl1, xr1, h1, N);
  }

  // ---- layer 2 ----
  transform2_k<<<(N + 63) / 64, 256, 0, stream>>>(h1, wl2, wr2, xl2, xr2, N);
  {
    int blocks2 = (N + 15) / 16;               // 4 waves/block * 4 nodes/wave
    gat2_k<<<blocks2, 256, 0, stream>>>(rowptr, csr_src, ea_h, we2, at2, b2,
                                        xl2, xr2, h2, N);
  }

  // ---- fused pool + fc ----
  pool_fc_k<<<G, 256, 0, stream>>>(h2, bat, wfc, bfc, (float*)d_out, N);
}

// Round 14
// 513.515 us; speedup vs baseline: 1.0523x; 1.0523x over previous
//
#include <hip/hip_runtime.h>
#include <hip/hip_bf16.h>
#include <hip/hip_fp16.h>

#define NEG_SLOPE 0.2f
#define LOG2E 1.4426950408889634f

typedef _Float16 h2v __attribute__((ext_vector_type(2)));

// ------------------------------------------------------------ CSR build
// exclusive scan, 3 phases (N <= 512*256)
__global__ void scan1_k(const int* __restrict__ deg, int* __restrict__ rowptr,
                        int* __restrict__ aux, int N) {
  __shared__ int sh[256];
  int t = threadIdx.x, i = blockIdx.x * 256 + t;
  int v = (i < N) ? deg[i] : 0;
  sh[t] = v; __syncthreads();
  for (int off = 1; off < 256; off <<= 1) {
    int x = (t >= off) ? sh[t - off] : 0;
    __syncthreads();
    sh[t] += x;
    __syncthreads();
  }
  if (i < N) rowptr[i] = sh[t] - v;
  if (t == 255) aux[blockIdx.x] = sh[255];
}

__global__ void scan2_k(int* __restrict__ aux, int naux) {
  __shared__ int sh[512];
  int t = threadIdx.x;
  int v = (t < naux) ? aux[t] : 0;
  sh[t] = v; __syncthreads();
  for (int off = 1; off < 512; off <<= 1) {
    int x = (t >= off) ? sh[t - off] : 0;
    __syncthreads();
    sh[t] += x;
    __syncthreads();
  }
  if (t < naux) aux[t] = sh[t] - v;
}

__global__ void scan3_k(int* __restrict__ rowptr, int* __restrict__ cursor,
                        const int* __restrict__ aux, int N, int E) {
  int i = blockIdx.x * blockDim.x + threadIdx.x;
  if (i < N) {
    int r = rowptr[i] + aux[i >> 8];
    rowptr[i] = r;
    cursor[i] = r;
  } else if (i == N) {
    rowptr[N] = E;
  }
}

// scatter: builds csr_src AND permuted fp16 edge-attrs (CSR order, 32B/edge)
__global__ void scatter_k(const int* __restrict__ srcA, const int* __restrict__ dstA,
                          const float* __restrict__ ea, int* __restrict__ cursor,
                          int* __restrict__ csr_src, uint4* __restrict__ ea_h, int E) {
  int e = blockIdx.x * blockDim.x + threadIdx.x;
  if (e >= E) return;
  int pos = atomicAdd(&cursor[dstA[e]], 1);
  csr_src[pos] = srcA[e];
  const float* p = ea + (size_t)e * 16;
  union { __half2 h2[8]; uint4 u[2]; } cv;
#pragma unroll
  for (int k = 0; k < 8; ++k) cv.h2[k] = __floats2half2_rn(p[2 * k], p[2 * k + 1]);
  uint4* d = ea_h + (size_t)pos * 2;
  d[0] = cv.u[0];
  d[1] = cv.u[1];
}

// ------------------------------------------------- FUSED: deg_count ∥ transform1
// blocks [0, degBlocks): degree count (4 edges/thread); blocks [degBlocks, ...): transform1 tiles.
__global__ __launch_bounds__(256) void t1deg_k(
    const float* __restrict__ x, const float* __restrict__ wl, const float* __restrict__ wr,
    float* __restrict__ xl, float* __restrict__ xr, int N,
    const int* __restrict__ dstA, int* __restrict__ deg, int E, int degBlocks) {
  __shared__ float wS[128 * 128];
  __shared__ float xs[32 * 128];
  int t = threadIdx.x;
  if ((int)blockIdx.x < degBlocks) {
    int base = blockIdx.x * 1024 + t;
#pragma unroll
    for (int k = 0; k < 4; ++k) {
      int e = base + k * 256;
      if (e < E) atomicAdd(&deg[dstA[e]], 1);
    }
    return;
  }
  int tile = blockIdx.x - degBlocks;
  for (int i = t; i < 128 * 64; i += 256) {
    int k = i >> 6, j = i & 63;
    wS[k * 128 + j]      = wl[i];
    wS[k * 128 + 64 + j] = wr[i];
  }
  __syncthreads();
  int tc = t & 31;
  int tr = t >> 5;
  {
    int base = tile << 5;
    const float4* x4 = (const float4*)x;
    float4* xs4 = (float4*)xs;
    for (int i = t; i < 1024; i += 256) {
      int node = base + (i >> 5);
      float4 v = {0.f, 0.f, 0.f, 0.f};
      if (node < N) v = x4[(size_t)node * 32 + (i & 31)];
      xs4[i] = v;
    }
    __syncthreads();
    float4 acc0 = {0,0,0,0}, acc1 = {0,0,0,0}, acc2 = {0,0,0,0}, acc3 = {0,0,0,0};
    const float* xrow = &xs[tr * 4 * 128];
#pragma unroll 4
    for (int k = 0; k < 128; ++k) {
      float4 w4 = *(const float4*)&wS[k * 128 + tc * 4];
      float x0 = xrow[k], x1 = xrow[128 + k], x2 = xrow[256 + k], x3 = xrow[384 + k];
      acc0.x += x0 * w4.x; acc0.y += x0 * w4.y; acc0.z += x0 * w4.z; acc0.w += x0 * w4.w;
      acc1.x += x1 * w4.x; acc1.y += x1 * w4.y; acc1.z += x1 * w4.z; acc1.w += x1 * w4.w;
      acc2.x += x2 * w4.x; acc2.y += x2 * w4.y; acc2.z += x2 * w4.z; acc2.w += x2 * w4.w;
      acc3.x += x3 * w4.x; acc3.y += x3 * w4.y; acc3.z += x3 * w4.z; acc3.w += x3 * w4.w;
    }
    float* dp = (tc < 16) ? xl : xr;
    int j4 = (tc & 15) * 4;
    int nb = base + tr * 4;
    if (nb + 0 < N) *(float4*)&dp[(size_t)(nb + 0) * 64 + j4] = acc0;
    if (nb + 1 < N) *(float4*)&dp[(size_t)(nb + 1) * 64 + j4] = acc1;
    if (nb + 2 < N) *(float4*)&dp[(size_t)(nb + 2) * 64 + j4] = acc2;
    if (nb + 3 < N) *(float4*)&dp[(size_t)(nb + 3) * 64 + j4] = acc3;
  }
}

// ------------------------------------------------- layer2 node transform (64 -> 32|32)
__global__ __launch_bounds__(256) void transform2_k(
    const float* __restrict__ h, const float* __restrict__ wl, const float* __restrict__ wr,
    float* __restrict__ xl, float* __restrict__ xr, int N) {
  __shared__ float wS[64 * 64];
  __shared__ float xs[64 * 64];
  int t = threadIdx.x;
  for (int i = t; i < 64 * 32; i += 256) {
    int k = i >> 5, j = i & 31;
    wS[k * 64 + j]      = wl[i];
    wS[k * 64 + 32 + j] = wr[i];
  }
  __syncthreads();
  int tc = t & 15;
  int tr = t >> 4;
  int ntiles = (N + 63) >> 6;
  for (int tile = blockIdx.x; tile < ntiles; tile += gridDim.x) {
    int base = tile << 6;
    const float4* h4 = (const float4*)h;
    float4* xs4 = (float4*)xs;
    for (int i = t; i < 1024; i += 256) {
      int node = base + (i >> 4);
      float4 v = {0.f, 0.f, 0.f, 0.f};
      if (node < N) v = h4[(size_t)node * 16 + (i & 15)];
      xs4[i] = v;
    }
    __syncthreads();
    float4 acc0 = {0,0,0,0}, acc1 = {0,0,0,0}, acc2 = {0,0,0,0}, acc3 = {0,0,0,0};
    const float* xrow = &xs[tr * 4 * 64];
#pragma unroll 4
    for (int k = 0; k < 64; ++k) {
      float4 w4 = *(const float4*)&wS[k * 64 + tc * 4];
      float x0 = xrow[k], x1 = xrow[64 + k], x2 = xrow[128 + k], x3 = xrow[192 + k];
      acc0.x += x0 * w4.x; acc0.y += x0 * w4.y; acc0.z += x0 * w4.z; acc0.w += x0 * w4.w;
      acc1.x += x1 * w4.x; acc1.y += x1 * w4.y; acc1.z += x1 * w4.z; acc1.w += x1 * w4.w;
      acc2.x += x2 * w4.x; acc2.y += x2 * w4.y; acc2.z += x2 * w4.z; acc2.w += x2 * w4.w;
      acc3.x += x3 * w4.x; acc3.y += x3 * w4.y; acc3.z += x3 * w4.z; acc3.w += x3 * w4.w;
    }
    float* dp = (tc < 8) ? xl : xr;
    int j4 = (tc & 7) * 4;
    int nb = base + tr * 4;
    if (nb + 0 < N) *(float4*)&dp[(size_t)(nb + 0) * 32 + j4] = acc0;
    if (nb + 1 < N) *(float4*)&dp[(size_t)(nb + 1) * 32 + j4] = acc1;
    if (nb + 2 < N) *(float4*)&dp[(size_t)(nb + 2) * 32 + j4] = acc2;
    if (nb + 3 < N) *(float4*)&dp[(size_t)(nb + 3) * 32 + j4] = acc3;
    __syncthreads();
  }
}

// ------------------------------------------------- GAT layer1: one wave per node (pull)
__global__ __launch_bounds__(256) void gat1_k(
    const int* __restrict__ rowptr, const int* __restrict__ csr_src,
    const uint4* __restrict__ ea_h, const float* __restrict__ we,
    const float* __restrict__ att, const float* __restrict__ b,
    const float* __restrict__ xl, const float* __restrict__ xr,
    float* __restrict__ h, int N) {
  int t = threadIdx.x;
  int lane = t & 63;
  h2v wh[8];
#pragma unroll
  for (int k = 0; k < 8; ++k) {
    wh[k].x = (_Float16)we[(2 * k) * 64 + lane];
    wh[k].y = (_Float16)we[(2 * k + 1) * 64 + lane];
  }
  float att_r = att[lane] * LOG2E;
  float b_r = b[lane];
  int wid = (blockIdx.x * blockDim.x + t) >> 6;
  int n0 = wid * 4;
  for (int jj = 0; jj < 4; ++jj) {
    int n = n0 + jj;
    if (n >= N) break;
    float xr_v = xr[(size_t)n * 64 + lane];
    float xl_s = xl[(size_t)n * 64 + lane];
    float num = 0.f, den = 0.f, efsum = 0.f;
    int rs = __builtin_amdgcn_readfirstlane(rowptr[n]);
    int re = __builtin_amdgcn_readfirstlane(rowptr[n + 1]);
    for (int base = rs; base < re; base += 64) {
      int cnt = min(64, re - base);
      int s_l = 0;
      if (lane < cnt) s_l = csr_src[base + lane];
      int i = 0;
      for (; i + 1 < cnt; i += 2) {
        int sa = __builtin_amdgcn_readlane(s_l, i);
        int sb = __builtin_amdgcn_readlane(s_l, i + 1);
        const float* pa = xl + (size_t)sa * 64;
        const float* pb = xl + (size_t)sb * 64;
        float xa = pa[lane];
        float xb = pb[lane];
        const uint4* epa = ea_h + (size_t)(base + i) * 2;
        union { uint4 u; h2v h[4]; } a0, a1, c0, c1;
        a0.u = epa[0]; a1.u = epa[1];
        c0.u = epa[2]; c1.u = epa[3];        // edge i+1 contiguous
        float fa0 = 0.f, fa1 = 0.f, fb0 = 0.f, fb1 = 0.f;
        fa0 = __builtin_amdgcn_fdot2(a0.h[0], wh[0], fa0, false);
        fb0 = __builtin_amdgcn_fdot2(c0.h[0], wh[0], fb0, false);
        fa1 = __builtin_amdgcn_fdot2(a0.h[1], wh[1], fa1, false);
        fb1 = __builtin_amdgcn_fdot2(c0.h[1], wh[1], fb1, false);
        fa0 = __builtin_amdgcn_fdot2(a0.h[2], wh[2], fa0, false);
        fb0 = __builtin_amdgcn_fdot2(c0.h[2], wh[2], fb0, false);
        fa1 = __builtin_amdgcn_fdot2(a0.h[3], wh[3], fa1, false);
        fb1 = __builtin_amdgcn_fdot2(c0.h[3], wh[3], fb1, false);
        fa0 = __builtin_amdgcn_fdot2(a1.h[0], wh[4], fa0, false);
        fb0 = __builtin_amdgcn_fdot2(c1.h[0], wh[4], fb0, false);
        fa1 = __builtin_amdgcn_fdot2(a1.h[1], wh[5], fa1, false);
        fb1 = __builtin_amdgcn_fdot2(c1.h[1], wh[5], fb1, false);
        fa0 = __builtin_amdgcn_fdot2(a1.h[2], wh[6], fa0, false);
        fb0 = __builtin_amdgcn_fdot2(c1.h[2], wh[6], fb0, false);
        fa1 = __builtin_amdgcn_fdot2(a1.h[3], wh[7], fa1, false);
        fb1 = __builtin_amdgcn_fdot2(c1.h[3], wh[7], fb1, false);
        float fa = fa0 + fa1, fb = fb0 + fb1;
        float ma = xa + xr_v + fa; ma = fmaxf(ma, NEG_SLOPE * ma);
        float mb = xb + xr_v + fb; mb = fmaxf(mb, NEG_SLOPE * mb);
        float ta = ma * att_r, tb = mb * att_r;
#pragma unroll
        for (int off = 1; off < 32; off <<= 1) {
          ta += __shfl_xor(ta, off);
          tb += __shfl_xor(tb, off);
        }
        float ga = __builtin_amdgcn_exp2f(ta), gb = __builtin_amdgcn_exp2f(tb);
        num += ga * xa + gb * xb;
        den += ga + gb;
        efsum += fa + fb;
      }
      if (i < cnt) {                          // single tail edge, unmasked
        int sa = __builtin_amdgcn_readlane(s_l, i);
        const float* pa = xl + (size_t)sa * 64;
        float xa = pa[lane];
        const uint4* epa = ea_h + (size_t)(base + i) * 2;
        union { uint4 u; h2v h[4]; } a0, a1;
        a0.u = epa[0]; a1.u = epa[1];
        float fa0 = 0.f, fa1 = 0.f;
        fa0 = __builtin_amdgcn_fdot2(a0.h[0], wh[0], fa0, false);
        fa1 = __builtin_amdgcn_fdot2(a0.h[1], wh[1], fa1, false);
        fa0 = __builtin_amdgcn_fdot2(a0.h[2], wh[2], fa0, false);
        fa1 = __builtin_amdgcn_fdot2(a0.h[3], wh[3], fa1, false);
        fa0 = __builtin_amdgcn_fdot2(a1.h[0], wh[4], fa0, false);
        fa1 = __builtin_amdgcn_fdot2(a1.h[1], wh[5], fa1, false);
        fa0 = __builtin_amdgcn_fdot2(a1.h[2], wh[6], fa0, false);
        fa1 = __builtin_amdgcn_fdot2(a1.h[3], wh[7], fa1, false);
        float fa = fa0 + fa1;
        float ma = xa + xr_v + fa; ma = fmaxf(ma, NEG_SLOPE * ma);
        float ta = ma * att_r;
#pragma unroll
        for (int off = 1; off < 32; off <<= 1) ta += __shfl_xor(ta, off);
        float ga = __builtin_amdgcn_exp2f(ta);
        num += ga * xa;
        den += ga;
        efsum += fa;
      }
    }
    // self loop: ef_self = mean(ea@we) = efsum/deg
    int deg = re - rs;
    float ef_self = efsum * __builtin_amdgcn_rcpf(fmaxf((float)deg, 1.f));
    float mm = xl_s + xr_v + ef_self;
    mm = fmaxf(mm, NEG_SLOPE * mm);
    float s2 = mm * att_r;
#pragma unroll
    for (int off = 1; off < 32; off <<= 1) s2 += __shfl_xor(s2, off);
    float e2 = __builtin_amdgcn_exp2f(s2);
    num += e2 * xl_s;
    den += e2;
    h[(size_t)n * 64 + lane] = fmaxf(num * __builtin_amdgcn_rcpf(fmaxf(den, 1e-16f)) + b_r, 0.f);
  }
}

// ------------------------------------------------- GAT layer2: half-wave per node (R12)
__global__ __launch_bounds__(256) void gat2_k(
    const int* __restrict__ rowptr, const int* __restrict__ csr_src,
    const uint4* __restrict__ ea_h, const float* __restrict__ we,
    const float* __restrict__ att, const float* __restrict__ b,
    const float* __restrict__ xl, const float* __restrict__ xr,
    float* __restrict__ h, int N) {
  int t = threadIdx.x;
  int lane = t & 63;
  int c = lane & 31;
  int half = lane >> 5;
  int hbase = lane & 32;
  h2v wh[8];
#pragma unroll
  for (int k = 0; k < 8; ++k) {
    wh[k].x = (_Float16)we[(2 * k) * 32 + c];
    wh[k].y = (_Float16)we[(2 * k + 1) * 32 + c];
  }
  float att_r = att[c] * LOG2E;
  float b_r = b[c];
  int wid = (blockIdx.x * blockDim.x + t) >> 6;
  int p0 = wid * 4;
  for (int jj = 0; jj < 4; ++jj) {
    int p = p0 + jj;
    if (p * 2 >= N) break;
    int n = p * 2 + half;
    if (n >= N) continue;
    float xr_v = xr[(size_t)n * 32 + c];
    float xl_s = xl[(size_t)n * 32 + c];
    float num = 0.f, den = 0.f, efsum = 0.f;
    int rs = rowptr[n], re = rowptr[n + 1];
    for (int base = rs; base < re; base += 32) {
      int cnt = min(32, re - base);
      int s_l = 0;
      if (c < cnt) s_l = csr_src[base + c];
      int i = 0;
      for (; i + 1 < cnt; i += 2) {
        int sa = __shfl(s_l, hbase + i), sb = __shfl(s_l, hbase + i + 1);
        float xa = xl[(size_t)sa * 32 + c];
        float xb = xl[(size_t)sb * 32 + c];
        const uint4* epa = ea_h + (size_t)(base + i) * 2;
        union { uint4 u; h2v h[4]; } a0, a1, c0, c1;
        a0.u = epa[0]; a1.u = epa[1];
        c0.u = epa[2]; c1.u = epa[3];
        float fa0 = 0.f, fa1 = 0.f, fb0 = 0.f, fb1 = 0.f;
        fa0 = __builtin_amdgcn_fdot2(a0.h[0], wh[0], fa0, false);
        fb0 = __builtin_amdgcn_fdot2(c0.h[0], wh[0], fb0, false);
        fa1 = __builtin_amdgcn_fdot2(a0.h[1], wh[1], fa1, false);
        fb1 = __builtin_amdgcn_fdot2(c0.h[1], wh[1], fb1, false);
        fa0 = __builtin_amdgcn_fdot2(a0.h[2], wh[2], fa0, false);
        fb0 = __builtin_amdgcn_fdot2(c0.h[2], wh[2], fb0, false);
        fa1 = __builtin_amdgcn_fdot2(a0.h[3], wh[3], fa1, false);
        fb1 = __builtin_amdgcn_fdot2(c0.h[3], wh[3], fb1, false);
        fa0 = __builtin_amdgcn_fdot2(a1.h[0], wh[4], fa0, false);
        fb0 = __builtin_amdgcn_fdot2(c1.h[0], wh[4], fb0, false);
        fa1 = __builtin_amdgcn_fdot2(a1.h[1], wh[5], fa1, false);
        fb1 = __builtin_amdgcn_fdot2(c1.h[1], wh[5], fb1, false);
        fa0 = __builtin_amdgcn_fdot2(a1.h[2], wh[6], fa0, false);
        fb0 = __builtin_amdgcn_fdot2(c1.h[2], wh[6], fb0, false);
        fa1 = __builtin_amdgcn_fdot2(a1.h[3], wh[7], fa1, false);
        fb1 = __builtin_amdgcn_fdot2(c1.h[3], wh[7], fb1, false);
        float fa = fa0 + fa1, fb = fb0 + fb1;
        float ma = xa + xr_v + fa; ma = fmaxf(ma, NEG_SLOPE * ma);
        float mb = xb + xr_v + fb; mb = fmaxf(mb, NEG_SLOPE * mb);
        float ta = ma * att_r, tb = mb * att_r;
#pragma unroll
        for (int off = 1; off < 32; off <<= 1) {
          ta += __shfl_xor(ta, off);
          tb += __shfl_xor(tb, off);
        }
        float ga = __builtin_amdgcn_exp2f(ta), gb = __builtin_amdgcn_exp2f(tb);
        num += ga * xa + gb * xb;
        den += ga + gb;
        efsum += fa + fb;
      }
      if (i < cnt) {
        int sa = __shfl(s_l, hbase + i);
        float xa = xl[(size_t)sa * 32 + c];
        const uint4* epa = ea_h + (size_t)(base + i) * 2;
        union { uint4 u; h2v h[4]; } a0, a1;
        a0.u = epa[0]; a1.u = epa[1];
        float fa0 = 0.f, fa1 = 0.f;
        fa0 = __builtin_amdgcn_fdot2(a0.h[0], wh[0], fa0, false);
        fa1 = __builtin_amdgcn_fdot2(a0.h[1], wh[1], fa1, false);
        fa0 = __builtin_amdgcn_fdot2(a0.h[2], wh[2], fa0, false);
        fa1 = __builtin_amdgcn_fdot2(a0.h[3], wh[3], fa1, false);
        fa0 = __builtin_amdgcn_fdot2(a1.h[0], wh[4], fa0, false);
        fa1 = __builtin_amdgcn_fdot2(a1.h[1], wh[5], fa1, false);
        fa0 = __builtin_amdgcn_fdot2(a1.h[2], wh[6], fa0, false);
        fa1 = __builtin_amdgcn_fdot2(a1.h[3], wh[7], fa1, false);
        float fa = fa0 + fa1;
        float ma = xa + xr_v + fa; ma = fmaxf(ma, NEG_SLOPE * ma);
        float ta = ma * att_r;
#pragma unroll
        for (int off = 1; off < 32; off <<= 1) ta += __shfl_xor(ta, off);
        float ga = __builtin_amdgcn_exp2f(ta);
        num += ga * xa;
        den += ga;
        efsum += fa;
      }
    }
    int deg = re - rs;
    float ef_self = efsum * __builtin_amdgcn_rcpf(fmaxf((float)deg, 1.f));
    float mm = xl_s + xr_v + ef_self;
    mm = fmaxf(mm, NEG_SLOPE * mm);
    float s2 = mm * att_r;
#pragma unroll
    for (int off = 1; off < 32; off <<= 1) s2 += __shfl_xor(s2, off);
    float e2 = __builtin_amdgcn_exp2f(s2);
    num += e2 * xl_s;
    den += e2;
    h[(size_t)n * 32 + c] = fmaxf(num * __builtin_amdgcn_rcpf(fmaxf(den, 1e-16f)) + b_r, 0.f);
  }
}

// ------------------------------------------------- fused mean-pool + fc
__global__ __launch_bounds__(256) void pool_fc_k(
    const float* __restrict__ h, const int* __restrict__ batch,
    const float* __restrict__ wfc, const float* __restrict__ bfc,
    float* __restrict__ out, int N) {
  int g = blockIdx.x;
  __shared__ int srange[2];
  __shared__ float part[8][32];
  int t = threadIdx.x;
  if (t < 2) {
    int key = g + t;
    int lo = 0, hi = N;
    while (lo < hi) { int mid = (lo + hi) >> 1; if (batch[mid] < key) lo = mid + 1; else hi = mid; }
    srange[t] = lo;
  }
  __syncthreads();
  int rs = srange[0], re = srange[1];
  int c = t & 31, sub = t >> 5;
  float acc = 0.f;
  for (int n = rs + sub; n < re; n += 8) acc += h[(size_t)n * 32 + c];
  part[sub][c] = acc;
  __syncthreads();
  if (sub == 0) {
    float s = part[0][c];
#pragma unroll
    for (int i = 1; i < 8; ++i) s += part[i][c];
    part[0][c] = s / fmaxf((float)(re - rs), 1.f);
  }
  __syncthreads();
  if (sub == 0) {
    float a = 0.f;
#pragma unroll
    for (int k = 0; k < 32; ++k) a += part[0][k] * wfc[k * 32 + c];
    out[g * 32 + c] = a + bfc[c];
  }
}

// ----------------------------------------------------------------- launcher
extern "C" void kernel_launch(void* const* d_in, const int* in_sizes, int n_in,
                              void* d_out, int out_size, void* d_ws, size_t ws_size,
                              hipStream_t stream) {
  const float* x   = (const float*)d_in[0];
  const int*   ei  = (const int*)d_in[1];
  const float* ea  = (const float*)d_in[2];
  const int*   bat = (const int*)d_in[3];
  const float* wl1 = (const float*)d_in[4];
  const float* wr1 = (const float*)d_in[5];
  const float* we1 = (const float*)d_in[6];
  const float* at1 = (const float*)d_in[7];
  const float* b1  = (const float*)d_in[8];
  const float* wl2 = (const float*)d_in[9];
  const float* wr2 = (const float*)d_in[10];
  const float* we2 = (const float*)d_in[11];
  const float* at2 = (const float*)d_in[12];
  const float* b2  = (const float*)d_in[13];
  const float* wfc = (const float*)d_in[14];
  const float* bfc = (const float*)d_in[15];

  const int N = in_sizes[0] / 128;
  const int E = in_sizes[1] / 2;
  const int G = 256;
  const int* srcA = ei;
  const int* dstA = ei + E;

  // ---- workspace layout (~110 MB) ----
  uint4* ea_h   = (uint4*)d_ws;                      // E*2 uint4 (fp16 attrs)
  float* xl1    = (float*)(ea_h + (size_t)E * 2);    // N*64
  float* xr1    = xl1 + (size_t)N * 64;              // N*64
  int*   deg    = (int*)(xr1 + (size_t)N * 64);      // N
  int*   rowptr = deg + N;                           // N+1
  int*   cursor = rowptr + (N + 1);                  // N
  int*   aux    = cursor + N;                        // 512
  int*   csr_src= aux + 512;                         // E
  float* h1     = xr1;                               // in-place over xr1
  float* xl2    = xl1;                               // N*32
  float* xr2    = xl1 + (size_t)N * 32;              // N*32
  float* h2     = xr2;                               // in-place over xr2

  const int naux = (N + 255) / 256;
  const int degBlocks = (E + 1023) / 1024;
  const int ntiles1 = (N + 31) / 32;

  // ---- fused deg_count + transform1, then scans, then scatter ----
  hipMemsetAsync(deg, 0, (size_t)N * sizeof(int), stream);
  t1deg_k<<<degBlocks + ntiles1, 256, 0, stream>>>(x, wl1, wr1, xl1, xr1, N,
                                                   dstA, deg, E, degBlocks);
  scan1_k<<<naux, 256, 0, stream>>>(deg, rowptr, aux, N);
  scan2_k<<<1, 512, 0, stream>>>(aux, naux);
  scan3_k<<<(N + 256) / 256, 256, 0, stream>>>(rowptr, cursor, aux, N, E);
  scatter_k<<<(E + 255) / 256, 256, 0, stream>>>(srcA, dstA, ea, cursor, csr_src, ea_h, E);

  // ---- layer 1 ----
  {
    int blocks1 = (N + 15) / 16;               // 4 waves/block * 4 nodes/wave
    gat1_k<<<blocks1, 256, 0, stream>>>(rowptr, csr_src, ea_h, we1, at1, b1,
                                        xl1, xr1, h1, N);
  }

  // ---- layer 2 ----
  transform2_k<<<(N + 63) / 64, 256, 0, stream>>>(h1, wl2, wr2, xl2, xr2, N);
  {
    int P = (N + 1) / 2;
    int blocks2 = (P + 15) / 16;               // 4 waves/block * 4 pairs/wave
    gat2_k<<<blocks2, 256, 0, stream>>>(rowptr, csr_src, ea_h, we2, at2, b2,
                                        xl2, xr2, h2, N);
  }

  // ---- fused pool + fc ----
  pool_fc_k<<<G, 256, 0, stream>>>(h2, bat, wfc, bfc, (float*)d_out, N);
}

// Round 16
// 480.395 us; speedup vs baseline: 1.1248x; 1.0689x over previous
//
#include <hip/hip_runtime.h>
#include <hip/hip_bf16.h>
#include <hip/hip_fp16.h>

#define NEG_SLOPE 0.2f
#define LOG2E 1.4426950408889634f

typedef _Float16 h2v __attribute__((ext_vector_type(2)));
typedef __fp16 f16x2 __attribute__((ext_vector_type(2)));
union hu { h2v h; f16x2 f; unsigned int u; };

// ------------------------------------------------------------ CSR build
__global__ void scan1_k(const int* __restrict__ deg, int* __restrict__ rowptr,
                        int* __restrict__ aux, int N) {
  __shared__ int sh[256];
  int t = threadIdx.x, i = blockIdx.x * 256 + t;
  int v = (i < N) ? deg[i] : 0;
  sh[t] = v; __syncthreads();
  for (int off = 1; off < 256; off <<= 1) {
    int x = (t >= off) ? sh[t - off] : 0;
    __syncthreads();
    sh[t] += x;
    __syncthreads();
  }
  if (i < N) rowptr[i] = sh[t] - v;
  if (t == 255) aux[blockIdx.x] = sh[255];
}

__global__ void scan2_k(int* __restrict__ aux, int naux) {
  __shared__ int sh[512];
  int t = threadIdx.x;
  int v = (t < naux) ? aux[t] : 0;
  sh[t] = v; __syncthreads();
  for (int off = 1; off < 512; off <<= 1) {
    int x = (t >= off) ? sh[t - off] : 0;
    __syncthreads();
    sh[t] += x;
    __syncthreads();
  }
  if (t < naux) aux[t] = sh[t] - v;
}

__global__ void scan3_k(int* __restrict__ rowptr, int* __restrict__ cursor,
                        const int* __restrict__ aux, int N, int E) {
  int i = blockIdx.x * blockDim.x + threadIdx.x;
  if (i < N) {
    int r = rowptr[i] + aux[i >> 8];
    rowptr[i] = r;
    cursor[i] = r;
  } else if (i == N) {
    rowptr[N] = E;
  }
}

__global__ void scatter_k(const int* __restrict__ srcA, const int* __restrict__ dstA,
                          const float* __restrict__ ea, int* __restrict__ cursor,
                          int* __restrict__ csr_src, uint4* __restrict__ ea_h, int E) {
  int e = blockIdx.x * blockDim.x + threadIdx.x;
  if (e >= E) return;
  int pos = atomicAdd(&cursor[dstA[e]], 1);
  csr_src[pos] = srcA[e];
  const float* p = ea + (size_t)e * 16;
  union { __half2 h2[8]; uint4 u[2]; } cv;
#pragma unroll
  for (int k = 0; k < 8; ++k) cv.h2[k] = __floats2half2_rn(p[2 * k], p[2 * k + 1]);
  uint4* d = ea_h + (size_t)pos * 2;
  d[0] = cv.u[0];
  d[1] = cv.u[1];
}

// ------------------------------------------------- FUSED: deg_count ∥ transform1 (fp16/fdot2)
// blocks [0,degBlocks): degree count; rest: one 32-node tile each.
// wS: [64 kp][128 col] packed fp16 (32KB); xs: [32 node][64 kp] packed (8KB).
__global__ __launch_bounds__(256) void t1deg_k(
    const float* __restrict__ x, const float* __restrict__ wl, const float* __restrict__ wr,
    float* __restrict__ xl, float* __restrict__ xr, int N,
    const int* __restrict__ dstA, int* __restrict__ deg, int E, int degBlocks) {
  __shared__ unsigned int wS[64 * 128];
  __shared__ unsigned int xs[32 * 64];
  int t = threadIdx.x;
  if ((int)blockIdx.x < degBlocks) {
    int base = blockIdx.x * 1024 + t;
#pragma unroll
    for (int k = 0; k < 4; ++k) {
      int e = base + k * 256;
      if (e < E) atomicAdd(&deg[dstA[e]], 1);
    }
    return;
  }
  int tile = blockIdx.x - degBlocks;
  for (int i = t; i < 64 * 64; i += 256) {       // 4096 per side
    int kp = i >> 6, j = i & 63;
    hu pl, pr;
    pl.f = __builtin_amdgcn_cvt_pkrtz(wl[(2 * kp) * 64 + j], wl[(2 * kp + 1) * 64 + j]);
    pr.f = __builtin_amdgcn_cvt_pkrtz(wr[(2 * kp) * 64 + j], wr[(2 * kp + 1) * 64 + j]);
    wS[kp * 128 + j]      = pl.u;
    wS[kp * 128 + 64 + j] = pr.u;
  }
  {
    int base = tile << 5;
    const float4* x4 = (const float4*)x;
    for (int i = t; i < 1024; i += 256) {        // 32 nodes * 32 float4
      int node = base + (i >> 5);
      float4 v = {0.f, 0.f, 0.f, 0.f};
      if (node < N) v = x4[(size_t)node * 32 + (i & 31)];
      hu p0, p1;
      p0.f = __builtin_amdgcn_cvt_pkrtz(v.x, v.y);
      p1.f = __builtin_amdgcn_cvt_pkrtz(v.z, v.w);
      uint2* d = (uint2*)&xs[(i >> 5) * 64 + (i & 31) * 2];
      *d = make_uint2(p0.u, p1.u);
    }
    __syncthreads();
    int tc = t & 31;                             // 32 col-groups * 4 cols
    int tr = t >> 5;                             // 8 node-groups * 4 nodes
    float4 acc0 = {0,0,0,0}, acc1 = {0,0,0,0}, acc2 = {0,0,0,0}, acc3 = {0,0,0,0};
    const unsigned int* xrow = &xs[tr * 4 * 64];
#pragma unroll 4
    for (int kp = 0; kp < 64; ++kp) {
      uint4 wu = *(const uint4*)&wS[kp * 128 + tc * 4];
      hu w0, w1, w2, w3, q0, q1, q2, q3;
      w0.u = wu.x; w1.u = wu.y; w2.u = wu.z; w3.u = wu.w;
      q0.u = xrow[kp]; q1.u = xrow[64 + kp]; q2.u = xrow[128 + kp]; q3.u = xrow[192 + kp];
      acc0.x = __builtin_amdgcn_fdot2(q0.h, w0.h, acc0.x, false);
      acc0.y = __builtin_amdgcn_fdot2(q0.h, w1.h, acc0.y, false);
      acc0.z = __builtin_amdgcn_fdot2(q0.h, w2.h, acc0.z, false);
      acc0.w = __builtin_amdgcn_fdot2(q0.h, w3.h, acc0.w, false);
      acc1.x = __builtin_amdgcn_fdot2(q1.h, w0.h, acc1.x, false);
      acc1.y = __builtin_amdgcn_fdot2(q1.h, w1.h, acc1.y, false);
      acc1.z = __builtin_amdgcn_fdot2(q1.h, w2.h, acc1.z, false);
      acc1.w = __builtin_amdgcn_fdot2(q1.h, w3.h, acc1.w, false);
      acc2.x = __builtin_amdgcn_fdot2(q2.h, w0.h, acc2.x, false);
      acc2.y = __builtin_amdgcn_fdot2(q2.h, w1.h, acc2.y, false);
      acc2.z = __builtin_amdgcn_fdot2(q2.h, w2.h, acc2.z, false);
      acc2.w = __builtin_amdgcn_fdot2(q2.h, w3.h, acc2.w, false);
      acc3.x = __builtin_amdgcn_fdot2(q3.h, w0.h, acc3.x, false);
      acc3.y = __builtin_amdgcn_fdot2(q3.h, w1.h, acc3.y, false);
      acc3.z = __builtin_amdgcn_fdot2(q3.h, w2.h, acc3.z, false);
      acc3.w = __builtin_amdgcn_fdot2(q3.h, w3.h, acc3.w, false);
    }
    float* dp = (tc < 16) ? xl : xr;
    int j4 = (tc & 15) * 4;
    int nb = base + tr * 4;
    if (nb + 0 < N) *(float4*)&dp[(size_t)(nb + 0) * 64 + j4] = acc0;
    if (nb + 1 < N) *(float4*)&dp[(size_t)(nb + 1) * 64 + j4] = acc1;
    if (nb + 2 < N) *(float4*)&dp[(size_t)(nb + 2) * 64 + j4] = acc2;
    if (nb + 3 < N) *(float4*)&dp[(size_t)(nb + 3) * 64 + j4] = acc3;
  }
}

// ------------------------------------------------- layer2 node transform (fp16/fdot2)
// wS: [32 kp][64 col] packed (8KB); xs: [64 node][32 kp] packed (8KB).
__global__ __launch_bounds__(256) void transform2_k(
    const float* __restrict__ h, const float* __restrict__ wl, const float* __restrict__ wr,
    float* __restrict__ xl, float* __restrict__ xr, int N) {
  __shared__ unsigned int wS[32 * 64];
  __shared__ unsigned int xs[64 * 32];
  int t = threadIdx.x;
  for (int i = t; i < 32 * 32; i += 256) {       // 1024 per side
    int kp = i >> 5, j = i & 31;
    hu pl, pr;
    pl.f = __builtin_amdgcn_cvt_pkrtz(wl[(2 * kp) * 32 + j], wl[(2 * kp + 1) * 32 + j]);
    pr.f = __builtin_amdgcn_cvt_pkrtz(wr[(2 * kp) * 32 + j], wr[(2 * kp + 1) * 32 + j]);
    wS[kp * 64 + j]      = pl.u;
    wS[kp * 64 + 32 + j] = pr.u;
  }
  {
    int tile = blockIdx.x;
    int base = tile << 6;
    const float4* h4 = (const float4*)h;
    for (int i = t; i < 1024; i += 256) {        // 64 nodes * 16 float4
      int node = base + (i >> 4);
      float4 v = {0.f, 0.f, 0.f, 0.f};
      if (node < N) v = h4[(size_t)node * 16 + (i & 15)];
      hu p0, p1;
      p0.f = __builtin_amdgcn_cvt_pkrtz(v.x, v.y);
      p1.f = __builtin_amdgcn_cvt_pkrtz(v.z, v.w);
      uint2* d = (uint2*)&xs[(i >> 4) * 32 + (i & 15) * 2];
      *d = make_uint2(p0.u, p1.u);
    }
    __syncthreads();
    int tc = t & 15;                             // 16 col-groups * 4 cols
    int tr = t >> 4;                             // 16 node-groups * 4 nodes
    float4 acc0 = {0,0,0,0}, acc1 = {0,0,0,0}, acc2 = {0,0,0,0}, acc3 = {0,0,0,0};
    const unsigned int* xrow = &xs[tr * 4 * 32];
#pragma unroll 4
    for (int kp = 0; kp < 32; ++kp) {
      uint4 wu = *(const uint4*)&wS[kp * 64 + tc * 4];
      hu w0, w1, w2, w3, q0, q1, q2, q3;
      w0.u = wu.x; w1.u = wu.y; w2.u = wu.z; w3.u = wu.w;
      q0.u = xrow[kp]; q1.u = xrow[32 + kp]; q2.u = xrow[64 + kp]; q3.u = xrow[96 + kp];
      acc0.x = __builtin_amdgcn_fdot2(q0.h, w0.h, acc0.x, false);
      acc0.y = __builtin_amdgcn_fdot2(q0.h, w1.h, acc0.y, false);
      acc0.z = __builtin_amdgcn_fdot2(q0.h, w2.h, acc0.z, false);
      acc0.w = __builtin_amdgcn_fdot2(q0.h, w3.h, acc0.w, false);
      acc1.x = __builtin_amdgcn_fdot2(q1.h, w0.h, acc1.x, false);
      acc1.y = __builtin_amdgcn_fdot2(q1.h, w1.h, acc1.y, false);
      acc1.z = __builtin_amdgcn_fdot2(q1.h, w2.h, acc1.z, false);
      acc1.w = __builtin_amdgcn_fdot2(q1.h, w3.h, acc1.w, false);
      acc2.x = __builtin_amdgcn_fdot2(q2.h, w0.h, acc2.x, false);
      acc2.y = __builtin_amdgcn_fdot2(q2.h, w1.h, acc2.y, false);
      acc2.z = __builtin_amdgcn_fdot2(q2.h, w2.h, acc2.z, false);
      acc2.w = __builtin_amdgcn_fdot2(q2.h, w3.h, acc2.w, false);
      acc3.x = __builtin_amdgcn_fdot2(q3.h, w0.h, acc3.x, false);
      acc3.y = __builtin_amdgcn_fdot2(q3.h, w1.h, acc3.y, false);
      acc3.z = __builtin_amdgcn_fdot2(q3.h, w2.h, acc3.z, false);
      acc3.w = __builtin_amdgcn_fdot2(q3.h, w3.h, acc3.w, false);
    }
    float* dp = (tc < 8) ? xl : xr;
    int j4 = (tc & 7) * 4;
    int nb = base + tr * 4;
    if (nb + 0 < N) *(float4*)&dp[(size_t)(nb + 0) * 32 + j4] = acc0;
    if (nb + 1 < N) *(float4*)&dp[(size_t)(nb + 1) * 32 + j4] = acc1;
    if (nb + 2 < N) *(float4*)&dp[(size_t)(nb + 2) * 32 + j4] = acc2;
    if (nb + 3 < N) *(float4*)&dp[(size_t)(nb + 3) * 32 + j4] = acc3;
  }
}

// ------------------------------------------------- GAT layer1: one wave per node (pull)
__global__ __launch_bounds__(256) void gat1_k(
    const int* __restrict__ rowptr, const int* __restrict__ csr_src,
    const uint4* __restrict__ ea_h, const float* __restrict__ we,
    const float* __restrict__ att, const float* __restrict__ b,
    const float* __restrict__ xl, const float* __restrict__ xr,
    float* __restrict__ h, int N) {
  int t = threadIdx.x;
  int lane = t & 63;
  h2v wh[8];
#pragma unroll
  for (int k = 0; k < 8; ++k) {
    wh[k].x = (_Float16)we[(2 * k) * 64 + lane];
    wh[k].y = (_Float16)we[(2 * k + 1) * 64 + lane];
  }
  float att_r = att[lane] * LOG2E;
  float b_r = b[lane];
  int wid = (blockIdx.x * blockDim.x + t) >> 6;
  int n0 = wid * 4;
  for (int jj = 0; jj < 4; ++jj) {
    int n = n0 + jj;
    if (n >= N) break;
    float xr_v = xr[(size_t)n * 64 + lane];
    float xl_s = xl[(size_t)n * 64 + lane];
    float num = 0.f, den = 0.f, efsum = 0.f;
    int rs = __builtin_amdgcn_readfirstlane(rowptr[n]);
    int re = __builtin_amdgcn_readfirstlane(rowptr[n + 1]);
    for (int base = rs; base < re; base += 64) {
      int cnt = min(64, re - base);
      int s_l = 0;
      if (lane < cnt) s_l = csr_src[base + lane];
      int i = 0;
      for (; i + 1 < cnt; i += 2) {
        int sa = __builtin_amdgcn_readlane(s_l, i);
        int sb = __builtin_amdgcn_readlane(s_l, i + 1);
        const float* pa = xl + (size_t)sa * 64;
        const float* pb = xl + (size_t)sb * 64;
        float xa = pa[lane];
        float xb = pb[lane];
        const uint4* epa = ea_h + (size_t)(base + i) * 2;
        union { uint4 u; h2v h[4]; } a0, a1, c0, c1;
        a0.u = epa[0]; a1.u = epa[1];
        c0.u = epa[2]; c1.u = epa[3];
        float fa0 = 0.f, fa1 = 0.f, fb0 = 0.f, fb1 = 0.f;
        fa0 = __builtin_amdgcn_fdot2(a0.h[0], wh[0], fa0, false);
        fb0 = __builtin_amdgcn_fdot2(c0.h[0], wh[0], fb0, false);
        fa1 = __builtin_amdgcn_fdot2(a0.h[1], wh[1], fa1, false);
        fb1 = __builtin_amdgcn_fdot2(c0.h[1], wh[1], fb1, false);
        fa0 = __builtin_amdgcn_fdot2(a0.h[2], wh[2], fa0, false);
        fb0 = __builtin_amdgcn_fdot2(c0.h[2], wh[2], fb0, false);
        fa1 = __builtin_amdgcn_fdot2(a0.h[3], wh[3], fa1, false);
        fb1 = __builtin_amdgcn_fdot2(c0.h[3], wh[3], fb1, false);
        fa0 = __builtin_amdgcn_fdot2(a1.h[0], wh[4], fa0, false);
        fb0 = __builtin_amdgcn_fdot2(c1.h[0], wh[4], fb0, false);
        fa1 = __builtin_amdgcn_fdot2(a1.h[1], wh[5], fa1, false);
        fb1 = __builtin_amdgcn_fdot2(c1.h[1], wh[5], fb1, false);
        fa0 = __builtin_amdgcn_fdot2(a1.h[2], wh[6], fa0, false);
        fb0 = __builtin_amdgcn_fdot2(c1.h[2], wh[6], fb0, false);
        fa1 = __builtin_amdgcn_fdot2(a1.h[3], wh[7], fa1, false);
        fb1 = __builtin_amdgcn_fdot2(c1.h[3], wh[7], fb1, false);
        float fa = fa0 + fa1, fb = fb0 + fb1;
        float ma = xa + xr_v + fa; ma = fmaxf(ma, NEG_SLOPE * ma);
        float mb = xb + xr_v + fb; mb = fmaxf(mb, NEG_SLOPE * mb);
        float ta = ma * att_r, tb = mb * att_r;
#pragma unroll
        for (int off = 1; off < 32; off <<= 1) {
          ta += __shfl_xor(ta, off);
          tb += __shfl_xor(tb, off);
        }
        float ga = __builtin_amdgcn_exp2f(ta), gb = __builtin_amdgcn_exp2f(tb);
        num += ga * xa + gb * xb;
        den += ga + gb;
        efsum += fa + fb;
      }
      if (i < cnt) {
        int sa = __builtin_amdgcn_readlane(s_l, i);
        const float* pa = xl + (size_t)sa * 64;
        float xa = pa[lane];
        const uint4* epa = ea_h + (size_t)(base + i) * 2;
        union { uint4 u; h2v h[4]; } a0, a1;
        a0.u = epa[0]; a1.u = epa[1];
        float fa0 = 0.f, fa1 = 0.f;
        fa0 = __builtin_amdgcn_fdot2(a0.h[0], wh[0], fa0, false);
        fa1 = __builtin_amdgcn_fdot2(a0.h[1], wh[1], fa1, false);
        fa0 = __builtin_amdgcn_fdot2(a0.h[2], wh[2], fa0, false);
        fa1 = __builtin_amdgcn_fdot2(a0.h[3], wh[3], fa1, false);
        fa0 = __builtin_amdgcn_fdot2(a1.h[0], wh[4], fa0, false);
        fa1 = __builtin_amdgcn_fdot2(a1.h[1], wh[5], fa1, false);
        fa0 = __builtin_amdgcn_fdot2(a1.h[2], wh[6], fa0, false);
        fa1 = __builtin_amdgcn_fdot2(a1.h[3], wh[7], fa1, false);
        float fa = fa0 + fa1;
        float ma = xa + xr_v + fa; ma = fmaxf(ma, NEG_SLOPE * ma);
        float ta = ma * att_r;
#pragma unroll
        for (int off = 1; off < 32; off <<= 1) ta += __shfl_xor(ta, off);
        float ga = __builtin_amdgcn_exp2f(ta);
        num += ga * xa;
        den += ga;
        efsum += fa;
      }
    }
    int deg = re - rs;
    float ef_self = efsum * __builtin_amdgcn_rcpf(fmaxf((float)deg, 1.f));
    float mm = xl_s + xr_v + ef_self;
    mm = fmaxf(mm, NEG_SLOPE * mm);
    float s2 = mm * att_r;
#pragma unroll
    for (int off = 1; off < 32; off <<= 1) s2 += __shfl_xor(s2, off);
    float e2 = __builtin_amdgcn_exp2f(s2);
    num += e2 * xl_s;
    den += e2;
    h[(size_t)n * 64 + lane] = fmaxf(num * __builtin_amdgcn_rcpf(fmaxf(den, 1e-16f)) + b_r, 0.f);
  }
}

// ------------------------------------------------- GAT layer2: half-wave per node (R12)
__global__ __launch_bounds__(256) void gat2_k(
    const int* __restrict__ rowptr, const int* __restrict__ csr_src,
    const uint4* __restrict__ ea_h, const float* __restrict__ we,
    const float* __restrict__ att, const float* __restrict__ b,
    const float* __restrict__ xl, const float* __restrict__ xr,
    float* __restrict__ h, int N) {
  int t = threadIdx.x;
  int lane = t & 63;
  int c = lane & 31;
  int half = lane >> 5;
  int hbase = lane & 32;
  h2v wh[8];
#pragma unroll
  for (int k = 0; k < 8; ++k) {
    wh[k].x = (_Float16)we[(2 * k) * 32 + c];
    wh[k].y = (_Float16)we[(2 * k + 1) * 32 + c];
  }
  float att_r = att[c] * LOG2E;
  float b_r = b[c];
  int wid = (blockIdx.x * blockDim.x + t) >> 6;
  int p0 = wid * 4;
  for (int jj = 0; jj < 4; ++jj) {
    int p = p0 + jj;
    if (p * 2 >= N) break;
    int n = p * 2 + half;
    if (n >= N) continue;
    float xr_v = xr[(size_t)n * 32 + c];
    float xl_s = xl[(size_t)n * 32 + c];
    float num = 0.f, den = 0.f, efsum = 0.f;
    int rs = rowptr[n], re = rowptr[n + 1];
    for (int base = rs; base < re; base += 32) {
      int cnt = min(32, re - base);
      int s_l = 0;
      if (c < cnt) s_l = csr_src[base + c];
      int i = 0;
      for (; i + 1 < cnt; i += 2) {
        int sa = __shfl(s_l, hbase + i), sb = __shfl(s_l, hbase + i + 1);
        float xa = xl[(size_t)sa * 32 + c];
        float xb = xl[(size_t)sb * 32 + c];
        const uint4* epa = ea_h + (size_t)(base + i) * 2;
        union { uint4 u; h2v h[4]; } a0, a1, c0, c1;
        a0.u = epa[0]; a1.u = epa[1];
        c0.u = epa[2]; c1.u = epa[3];
        float fa0 = 0.f, fa1 = 0.f, fb0 = 0.f, fb1 = 0.f;
        fa0 = __builtin_amdgcn_fdot2(a0.h[0], wh[0], fa0, false);
        fb0 = __builtin_amdgcn_fdot2(c0.h[0], wh[0], fb0, false);
        fa1 = __builtin_amdgcn_fdot2(a0.h[1], wh[1], fa1, false);
        fb1 = __builtin_amdgcn_fdot2(c0.h[1], wh[1], fb1, false);
        fa0 = __builtin_amdgcn_fdot2(a0.h[2], wh[2], fa0, false);
        fb0 = __builtin_amdgcn_fdot2(c0.h[2], wh[2], fb0, false);
        fa1 = __builtin_amdgcn_fdot2(a0.h[3], wh[3], fa1, false);
        fb1 = __builtin_amdgcn_fdot2(c0.h[3], wh[3], fb1, false);
        fa0 = __builtin_amdgcn_fdot2(a1.h[0], wh[4], fa0, false);
        fb0 = __builtin_amdgcn_fdot2(c1.h[0], wh[4], fb0, false);
        fa1 = __builtin_amdgcn_fdot2(a1.h[1], wh[5], fa1, false);
        fb1 = __builtin_amdgcn_fdot2(c1.h[1], wh[5], fb1, false);
        fa0 = __builtin_amdgcn_fdot2(a1.h[2], wh[6], fa0, false);
        fb0 = __builtin_amdgcn_fdot2(c1.h[2], wh[6], fb0, false);
        fa1 = __builtin_amdgcn_fdot2(a1.h[3], wh[7], fa1, false);
        fb1 = __builtin_amdgcn_fdot2(c1.h[3], wh[7], fb1, false);
        float fa = fa0 + fa1, fb = fb0 + fb1;
        float ma = xa + xr_v + fa; ma = fmaxf(ma, NEG_SLOPE * ma);
        float mb = xb + xr_v + fb; mb = fmaxf(mb, NEG_SLOPE * mb);
        float ta = ma * att_r, tb = mb * att_r;
#pragma unroll
        for (int off = 1; off < 32; off <<= 1) {
          ta += __shfl_xor(ta, off);
          tb += __shfl_xor(tb, off);
        }
        float ga = __builtin_amdgcn_exp2f(ta), gb = __builtin_amdgcn_exp2f(tb);
        num += ga * xa + gb * xb;
        den += ga + gb;
        efsum += fa + fb;
      }
      if (i < cnt) {
        int sa = __shfl(s_l, hbase + i);
        float xa = xl[(size_t)sa * 32 + c];
        const uint4* epa = ea_h + (size_t)(base + i) * 2;
        union { uint4 u; h2v h[4]; } a0, a1;
        a0.u = epa[0]; a1.u = epa[1];
        float fa0 = 0.f, fa1 = 0.f;
        fa0 = __builtin_amdgcn_fdot2(a0.h[0], wh[0], fa0, false);
        fa1 = __builtin_amdgcn_fdot2(a0.h[1], wh[1], fa1, false);
        fa0 = __builtin_amdgcn_fdot2(a0.h[2], wh[2], fa0, false);
        fa1 = __builtin_amdgcn_fdot2(a0.h[3], wh[3], fa1, false);
        fa0 = __builtin_amdgcn_fdot2(a1.h[0], wh[4], fa0, false);
        fa1 = __builtin_amdgcn_fdot2(a1.h[1], wh[5], fa1, false);
        fa0 = __builtin_amdgcn_fdot2(a1.h[2], wh[6], fa0, false);
        fa1 = __builtin_amdgcn_fdot2(a1.h[3], wh[7], fa1, false);
        float fa = fa0 + fa1;
        float ma = xa + xr_v + fa; ma = fmaxf(ma, NEG_SLOPE * ma);
        float ta = ma * att_r;
#pragma unroll
        for (int off = 1; off < 32; off <<= 1) ta += __shfl_xor(ta, off);
        float ga = __builtin_amdgcn_exp2f(ta);
        num += ga * xa;
        den += ga;
        efsum += fa;
      }
    }
    int deg = re - rs;
    float ef_self = efsum * __builtin_amdgcn_rcpf(fmaxf((float)deg, 1.f));
    float mm = xl_s + xr_v + ef_self;
    mm = fmaxf(mm, NEG_SLOPE * mm);
    float s2 = mm * att_r;
#pragma unroll
    for (int off = 1; off < 32; off <<= 1) s2 += __shfl_xor(s2, off);
    float e2 = __builtin_amdgcn_exp2f(s2);
    num += e2 * xl_s;
    den += e2;
    h[(size_t)n * 32 + c] = fmaxf(num * __builtin_amdgcn_rcpf(fmaxf(den, 1e-16f)) + b_r, 0.f);
  }
}

// ------------------------------------------------- fused mean-pool + fc
__global__ __launch_bounds__(256) void pool_fc_k(
    const float* __restrict__ h, const int* __restrict__ batch,
    const float* __restrict__ wfc, const float* __restrict__ bfc,
    float* __restrict__ out, int N) {
  int g = blockIdx.x;
  __shared__ int srange[2];
  __shared__ float part[8][32];
  int t = threadIdx.x;
  if (t < 2) {
    int key = g + t;
    int lo = 0, hi = N;
    while (lo < hi) { int mid = (lo + hi) >> 1; if (batch[mid] < key) lo = mid + 1; else hi = mid; }
    srange[t] = lo;
  }
  __syncthreads();
  int rs = srange[0], re = srange[1];
  int c = t & 31, sub = t >> 5;
  float acc = 0.f;
  for (int n = rs + sub; n < re; n += 8) acc += h[(size_t)n * 32 + c];
  part[sub][c] = acc;
  __syncthreads();
  if (sub == 0) {
    float s = part[0][c];
#pragma unroll
    for (int i = 1; i < 8; ++i) s += part[i][c];
    part[0][c] = s / fmaxf((float)(re - rs), 1.f);
  }
  __syncthreads();
  if (sub == 0) {
    float a = 0.f;
#pragma unroll
    for (int k = 0; k < 32; ++k) a += part[0][k] * wfc[k * 32 + c];
    out[g * 32 + c] = a + bfc[c];
  }
}

// ----------------------------------------------------------------- launcher
extern "C" void kernel_launch(void* const* d_in, const int* in_sizes, int n_in,
                              void* d_out, int out_size, void* d_ws, size_t ws_size,
                              hipStream_t stream) {
  const float* x   = (const float*)d_in[0];
  const int*   ei  = (const int*)d_in[1];
  const float* ea  = (const float*)d_in[2];
  const int*   bat = (const int*)d_in[3];
  const float* wl1 = (const float*)d_in[4];
  const float* wr1 = (const float*)d_in[5];
  const float* we1 = (const float*)d_in[6];
  const float* at1 = (const float*)d_in[7];
  const float* b1  = (const float*)d_in[8];
  const float* wl2 = (const float*)d_in[9];
  const float* wr2 = (const float*)d_in[10];
  const float* we2 = (const float*)d_in[11];
  const float* at2 = (const float*)d_in[12];
  const float* b2  = (const float*)d_in[13];
  const float* wfc = (const float*)d_in[14];
  const float* bfc = (const float*)d_in[15];

  const int N = in_sizes[0] / 128;
  const int E = in_sizes[1] / 2;
  const int G = 256;
  const int* srcA = ei;
  const int* dstA = ei + E;

  // ---- workspace layout (~110 MB) ----
  uint4* ea_h   = (uint4*)d_ws;                      // E*2 uint4 (fp16 attrs)
  float* xl1    = (float*)(ea_h + (size_t)E * 2);    // N*64
  float* xr1    = xl1 + (size_t)N * 64;              // N*64
  int*   deg    = (int*)(xr1 + (size_t)N * 64);      // N
  int*   rowptr = deg + N;                           // N+1
  int*   cursor = rowptr + (N + 1);                  // N
  int*   aux    = cursor + N;                        // 512
  int*   csr_src= aux + 512;                         // E
  float* h1     = xr1;                               // in-place over xr1
  float* xl2    = xl1;                               // N*32
  float* xr2    = xl1 + (size_t)N * 32;              // N*32
  float* h2     = xr2;                               // in-place over xr2

  const int naux = (N + 255) / 256;
  const int degBlocks = (E + 1023) / 1024;
  const int ntiles1 = (N + 31) / 32;

  // ---- fused deg_count + transform1, then scans, then scatter ----
  (void)hipMemsetAsync(deg, 0, (size_t)N * sizeof(int), stream);
  t1deg_k<<<degBlocks + ntiles1, 256, 0, stream>>>(x, wl1, wr1, xl1, xr1, N,
                                                   dstA, deg, E, degBlocks);
  scan1_k<<<naux, 256, 0, stream>>>(deg, rowptr, aux, N);
  scan2_k<<<1, 512, 0, stream>>>(aux, naux);
  scan3_k<<<(N + 256) / 256, 256, 0, stream>>>(rowptr, cursor, aux, N, E);
  scatter_k<<<(E + 255) / 256, 256, 0, stream>>>(srcA, dstA, ea, cursor, csr_src, ea_h, E);

  // ---- layer 1 ----
  {
    int blocks1 = (N + 15) / 16;
    gat1_k<<<blocks1, 256, 0, stream>>>(rowptr, csr_src, ea_h, we1, at1, b1,
                                        xl1, xr1, h1, N);
  }

  // ---- layer 2 ----
  transform2_k<<<(N + 63) / 64, 256, 0, stream>>>(h1, wl2, wr2, xl2, xr2, N);
  {
    int P = (N + 1) / 2;
    int blocks2 = (P + 15) / 16;
    gat2_k<<<blocks2, 256, 0, stream>>>(rowptr, csr_src, ea_h, we2, at2, b2,
                                        xl2, xr2, h2, N);
  }

  // ---- fused pool + fc ----
  pool_fc_k<<<G, 256, 0, stream>>>(h2, bat, wfc, bfc, (float*)d_out, N);
}

// Round 17
// 460.862 us; speedup vs baseline: 1.1725x; 1.0424x over previous
//
#include <hip/hip_runtime.h>
#include <hip/hip_bf16.h>
#include <hip/hip_fp16.h>

#define NEG_SLOPE 0.2f
#define LOG2E 1.4426950408889634f

typedef _Float16 h2v __attribute__((ext_vector_type(2)));
typedef __fp16 f16x2 __attribute__((ext_vector_type(2)));
union hu { h2v h; f16x2 f; unsigned int u; };

__device__ __forceinline__ float dot16h(uint4 u0, uint4 u1, const h2v* wh) {
  union { uint4 u; h2v h[4]; } a0, a1;
  a0.u = u0; a1.u = u1;
  float f0 = 0.f, f1 = 0.f;
  f0 = __builtin_amdgcn_fdot2(a0.h[0], wh[0], f0, false);
  f1 = __builtin_amdgcn_fdot2(a0.h[1], wh[1], f1, false);
  f0 = __builtin_amdgcn_fdot2(a0.h[2], wh[2], f0, false);
  f1 = __builtin_amdgcn_fdot2(a0.h[3], wh[3], f1, false);
  f0 = __builtin_amdgcn_fdot2(a1.h[0], wh[4], f0, false);
  f1 = __builtin_amdgcn_fdot2(a1.h[1], wh[5], f1, false);
  f0 = __builtin_amdgcn_fdot2(a1.h[2], wh[6], f0, false);
  f1 = __builtin_amdgcn_fdot2(a1.h[3], wh[7], f1, false);
  return f0 + f1;
}

// ------------------------------------------------------------ CSR build
__global__ void deg_count_k(const int* __restrict__ dstA, int* __restrict__ deg, int E) {
  int base = blockIdx.x * 1024 + threadIdx.x;
#pragma unroll
  for (int k = 0; k < 4; ++k) {
    int e = base + k * 256;
    if (e < E) atomicAdd(&deg[dstA[e]], 1);
  }
}

__global__ void scan1_k(const int* __restrict__ deg, int* __restrict__ rowptr,
                        int* __restrict__ aux, int N) {
  __shared__ int sh[256];
  int t = threadIdx.x, i = blockIdx.x * 256 + t;
  int v = (i < N) ? deg[i] : 0;
  sh[t] = v; __syncthreads();
  for (int off = 1; off < 256; off <<= 1) {
    int x = (t >= off) ? sh[t - off] : 0;
    __syncthreads();
    sh[t] += x;
    __syncthreads();
  }
  if (i < N) rowptr[i] = sh[t] - v;
  if (t == 255) aux[blockIdx.x] = sh[255];
}

__global__ void scan2_k(int* __restrict__ aux, int naux) {
  __shared__ int sh[512];
  int t = threadIdx.x;
  int v = (t < naux) ? aux[t] : 0;
  sh[t] = v; __syncthreads();
  for (int off = 1; off < 512; off <<= 1) {
    int x = (t >= off) ? sh[t - off] : 0;
    __syncthreads();
    sh[t] += x;
    __syncthreads();
  }
  if (t < naux) aux[t] = sh[t] - v;
}

__global__ void scan3_k(int* __restrict__ rowptr, int* __restrict__ cursor,
                        const int* __restrict__ aux, int N, int E) {
  int i = blockIdx.x * blockDim.x + threadIdx.x;
  if (i < N) {
    int r = rowptr[i] + aux[i >> 8];
    rowptr[i] = r;
    cursor[i] = r;
  } else if (i == N) {
    rowptr[N] = E;
  }
}

// ------------------------------------------------- FUSED: transform1 ∥ scatter
// blocks [0, ntiles1): transform1 (fp16/fdot2, one 32-node tile);
// blocks [ntiles1, ...): scatter (1 edge/thread) — overlaps the GEMM.
__global__ __launch_bounds__(256) void t1scat_k(
    const float* __restrict__ x, const float* __restrict__ wl, const float* __restrict__ wr,
    float* __restrict__ xl, float* __restrict__ xr, int N, int ntiles1,
    const int* __restrict__ srcA, const int* __restrict__ dstA,
    const float* __restrict__ ea, int* __restrict__ cursor,
    int* __restrict__ csr_src, uint4* __restrict__ ea_h, int E) {
  __shared__ unsigned int wS[64 * 128];
  __shared__ unsigned int xs[32 * 64];
  int t = threadIdx.x;
  if ((int)blockIdx.x >= ntiles1) {
    int e = (blockIdx.x - ntiles1) * 256 + t;
    if (e < E) {
      int pos = atomicAdd(&cursor[dstA[e]], 1);
      csr_src[pos] = srcA[e];
      const float* p = ea + (size_t)e * 16;
      union { __half2 h2[8]; uint4 u[2]; } cv;
#pragma unroll
      for (int k = 0; k < 8; ++k) cv.h2[k] = __floats2half2_rn(p[2 * k], p[2 * k + 1]);
      uint4* d = ea_h + (size_t)pos * 2;
      d[0] = cv.u[0];
      d[1] = cv.u[1];
    }
    return;
  }
  int tile = blockIdx.x;
  for (int i = t; i < 64 * 64; i += 256) {
    int kp = i >> 6, j = i & 63;
    hu pl, pr;
    pl.f = __builtin_amdgcn_cvt_pkrtz(wl[(2 * kp) * 64 + j], wl[(2 * kp + 1) * 64 + j]);
    pr.f = __builtin_amdgcn_cvt_pkrtz(wr[(2 * kp) * 64 + j], wr[(2 * kp + 1) * 64 + j]);
    wS[kp * 128 + j]      = pl.u;
    wS[kp * 128 + 64 + j] = pr.u;
  }
  {
    int base = tile << 5;
    const float4* x4 = (const float4*)x;
    for (int i = t; i < 1024; i += 256) {
      int node = base + (i >> 5);
      float4 v = {0.f, 0.f, 0.f, 0.f};
      if (node < N) v = x4[(size_t)node * 32 + (i & 31)];
      hu p0, p1;
      p0.f = __builtin_amdgcn_cvt_pkrtz(v.x, v.y);
      p1.f = __builtin_amdgcn_cvt_pkrtz(v.z, v.w);
      uint2* d = (uint2*)&xs[(i >> 5) * 64 + (i & 31) * 2];
      *d = make_uint2(p0.u, p1.u);
    }
    __syncthreads();
    int tc = t & 31;
    int tr = t >> 5;
    float4 acc0 = {0,0,0,0}, acc1 = {0,0,0,0}, acc2 = {0,0,0,0}, acc3 = {0,0,0,0};
    const unsigned int* xrow = &xs[tr * 4 * 64];
#pragma unroll 4
    for (int kp = 0; kp < 64; ++kp) {
      uint4 wu = *(const uint4*)&wS[kp * 128 + tc * 4];
      hu w0, w1, w2, w3, q0, q1, q2, q3;
      w0.u = wu.x; w1.u = wu.y; w2.u = wu.z; w3.u = wu.w;
      q0.u = xrow[kp]; q1.u = xrow[64 + kp]; q2.u = xrow[128 + kp]; q3.u = xrow[192 + kp];
      acc0.x = __builtin_amdgcn_fdot2(q0.h, w0.h, acc0.x, false);
      acc0.y = __builtin_amdgcn_fdot2(q0.h, w1.h, acc0.y, false);
      acc0.z = __builtin_amdgcn_fdot2(q0.h, w2.h, acc0.z, false);
      acc0.w = __builtin_amdgcn_fdot2(q0.h, w3.h, acc0.w, false);
      acc1.x = __builtin_amdgcn_fdot2(q1.h, w0.h, acc1.x, false);
      acc1.y = __builtin_amdgcn_fdot2(q1.h, w1.h, acc1.y, false);
      acc1.z = __builtin_amdgcn_fdot2(q1.h, w2.h, acc1.z, false);
      acc1.w = __builtin_amdgcn_fdot2(q1.h, w3.h, acc1.w, false);
      acc2.x = __builtin_amdgcn_fdot2(q2.h, w0.h, acc2.x, false);
      acc2.y = __builtin_amdgcn_fdot2(q2.h, w1.h, acc2.y, false);
      acc2.z = __builtin_amdgcn_fdot2(q2.h, w2.h, acc2.z, false);
      acc2.w = __builtin_amdgcn_fdot2(q2.h, w3.h, acc2.w, false);
      acc3.x = __builtin_amdgcn_fdot2(q3.h, w0.h, acc3.x, false);
      acc3.y = __builtin_amdgcn_fdot2(q3.h, w1.h, acc3.y, false);
      acc3.z = __builtin_amdgcn_fdot2(q3.h, w2.h, acc3.z, false);
      acc3.w = __builtin_amdgcn_fdot2(q3.h, w3.h, acc3.w, false);
    }
    float* dp = (tc < 16) ? xl : xr;
    int j4 = (tc & 15) * 4;
    int nb = base + tr * 4;
    if (nb + 0 < N) *(float4*)&dp[(size_t)(nb + 0) * 64 + j4] = acc0;
    if (nb + 1 < N) *(float4*)&dp[(size_t)(nb + 1) * 64 + j4] = acc1;
    if (nb + 2 < N) *(float4*)&dp[(size_t)(nb + 2) * 64 + j4] = acc2;
    if (nb + 3 < N) *(float4*)&dp[(size_t)(nb + 3) * 64 + j4] = acc3;
  }
}

// ------------------------------------------------- layer2 node transform (fp16/fdot2)
__global__ __launch_bounds__(256) void transform2_k(
    const float* __restrict__ h, const float* __restrict__ wl, const float* __restrict__ wr,
    float* __restrict__ xl, float* __restrict__ xr, int N) {
  __shared__ unsigned int wS[32 * 64];
  __shared__ unsigned int xs[64 * 32];
  int t = threadIdx.x;
  for (int i = t; i < 32 * 32; i += 256) {
    int kp = i >> 5, j = i & 31;
    hu pl, pr;
    pl.f = __builtin_amdgcn_cvt_pkrtz(wl[(2 * kp) * 32 + j], wl[(2 * kp + 1) * 32 + j]);
    pr.f = __builtin_amdgcn_cvt_pkrtz(wr[(2 * kp) * 32 + j], wr[(2 * kp + 1) * 32 + j]);
    wS[kp * 64 + j]      = pl.u;
    wS[kp * 64 + 32 + j] = pr.u;
  }
  {
    int base = blockIdx.x << 6;
    const float4* h4 = (const float4*)h;
    for (int i = t; i < 1024; i += 256) {
      int node = base + (i >> 4);
      float4 v = {0.f, 0.f, 0.f, 0.f};
      if (node < N) v = h4[(size_t)node * 16 + (i & 15)];
      hu p0, p1;
      p0.f = __builtin_amdgcn_cvt_pkrtz(v.x, v.y);
      p1.f = __builtin_amdgcn_cvt_pkrtz(v.z, v.w);
      uint2* d = (uint2*)&xs[(i >> 4) * 32 + (i & 15) * 2];
      *d = make_uint2(p0.u, p1.u);
    }
    __syncthreads();
    int tc = t & 15;
    int tr = t >> 4;
    float4 acc0 = {0,0,0,0}, acc1 = {0,0,0,0}, acc2 = {0,0,0,0}, acc3 = {0,0,0,0};
    const unsigned int* xrow = &xs[tr * 4 * 32];
#pragma unroll 4
    for (int kp = 0; kp < 32; ++kp) {
      uint4 wu = *(const uint4*)&wS[kp * 64 + tc * 4];
      hu w0, w1, w2, w3, q0, q1, q2, q3;
      w0.u = wu.x; w1.u = wu.y; w2.u = wu.z; w3.u = wu.w;
      q0.u = xrow[kp]; q1.u = xrow[32 + kp]; q2.u = xrow[64 + kp]; q3.u = xrow[96 + kp];
      acc0.x = __builtin_amdgcn_fdot2(q0.h, w0.h, acc0.x, false);
      acc0.y = __builtin_amdgcn_fdot2(q0.h, w1.h, acc0.y, false);
      acc0.z = __builtin_amdgcn_fdot2(q0.h, w2.h, acc0.z, false);
      acc0.w = __builtin_amdgcn_fdot2(q0.h, w3.h, acc0.w, false);
      acc1.x = __builtin_amdgcn_fdot2(q1.h, w0.h, acc1.x, false);
      acc1.y = __builtin_amdgcn_fdot2(q1.h, w1.h, acc1.y, false);
      acc1.z = __builtin_amdgcn_fdot2(q1.h, w2.h, acc1.z, false);
      acc1.w = __builtin_amdgcn_fdot2(q1.h, w3.h, acc1.w, false);
      acc2.x = __builtin_amdgcn_fdot2(q2.h, w0.h, acc2.x, false);
      acc2.y = __builtin_amdgcn_fdot2(q2.h, w1.h, acc2.y, false);
      acc2.z = __builtin_amdgcn_fdot2(q2.h, w2.h, acc2.z, false);
      acc2.w = __builtin_amdgcn_fdot2(q2.h, w3.h, acc2.w, false);
      acc3.x = __builtin_amdgcn_fdot2(q3.h, w0.h, acc3.x, false);
      acc3.y = __builtin_amdgcn_fdot2(q3.h, w1.h, acc3.y, false);
      acc3.z = __builtin_amdgcn_fdot2(q3.h, w2.h, acc3.z, false);
      acc3.w = __builtin_amdgcn_fdot2(q3.h, w3.h, acc3.w, false);
    }
    float* dp = (tc < 8) ? xl : xr;
    int j4 = (tc & 7) * 4;
    int nb = base + tr * 4;
    if (nb + 0 < N) *(float4*)&dp[(size_t)(nb + 0) * 32 + j4] = acc0;
    if (nb + 1 < N) *(float4*)&dp[(size_t)(nb + 1) * 32 + j4] = acc1;
    if (nb + 2 < N) *(float4*)&dp[(size_t)(nb + 2) * 32 + j4] = acc2;
    if (nb + 3 < N) *(float4*)&dp[(size_t)(nb + 3) * 32 + j4] = acc3;
  }
}

// ------------------------------------------------- GAT layer1: one wave per node (pull)
// 4-wide unmasked edge unroll (fp16 ea = 8 VGPR/pair) + unmasked single-edge tail.
__global__ __launch_bounds__(256) void gat1_k(
    const int* __restrict__ rowptr, const int* __restrict__ csr_src,
    const uint4* __restrict__ ea_h, const float* __restrict__ we,
    const float* __restrict__ att, const float* __restrict__ b,
    const float* __restrict__ xl, const float* __restrict__ xr,
    float* __restrict__ h, int N) {
  int t = threadIdx.x;
  int lane = t & 63;
  h2v wh[8];
#pragma unroll
  for (int k = 0; k < 8; ++k) {
    wh[k].x = (_Float16)we[(2 * k) * 64 + lane];
    wh[k].y = (_Float16)we[(2 * k + 1) * 64 + lane];
  }
  float att_r = att[lane] * LOG2E;
  float b_r = b[lane];
  int wid = (blockIdx.x * blockDim.x + t) >> 6;
  int n0 = wid * 4;
  for (int jj = 0; jj < 4; ++jj) {
    int n = n0 + jj;
    if (n >= N) break;
    float xr_v = xr[(size_t)n * 64 + lane];
    float xl_s = xl[(size_t)n * 64 + lane];
    float num = 0.f, den = 0.f, efsum = 0.f;
    int rs = __builtin_amdgcn_readfirstlane(rowptr[n]);
    int re = __builtin_amdgcn_readfirstlane(rowptr[n + 1]);
    for (int base = rs; base < re; base += 64) {
      int cnt = min(64, re - base);
      int s_l = 0;
      if (lane < cnt) s_l = csr_src[base + lane];
      int i = 0;
      for (; i + 3 < cnt; i += 4) {
        int sa = __builtin_amdgcn_readlane(s_l, i);
        int sb = __builtin_amdgcn_readlane(s_l, i + 1);
        int sc_ = __builtin_amdgcn_readlane(s_l, i + 2);
        int sd = __builtin_amdgcn_readlane(s_l, i + 3);
        float xa = (xl + (size_t)sa * 64)[lane];
        float xb = (xl + (size_t)sb * 64)[lane];
        float xc = (xl + (size_t)sc_ * 64)[lane];
        float xd = (xl + (size_t)sd * 64)[lane];
        const uint4* ep = ea_h + (size_t)(base + i) * 2;
        uint4 u0 = ep[0], u1 = ep[1], u2 = ep[2], u3 = ep[3];
        uint4 u4 = ep[4], u5 = ep[5], u6 = ep[6], u7 = ep[7];
        float fa = dot16h(u0, u1, wh);
        float fb = dot16h(u2, u3, wh);
        float fc = dot16h(u4, u5, wh);
        float fd = dot16h(u6, u7, wh);
        float ma = xa + xr_v + fa; ma = fmaxf(ma, NEG_SLOPE * ma);
        float mb = xb + xr_v + fb; mb = fmaxf(mb, NEG_SLOPE * mb);
        float mc = xc + xr_v + fc; mc = fmaxf(mc, NEG_SLOPE * mc);
        float md = xd + xr_v + fd; md = fmaxf(md, NEG_SLOPE * md);
        float ta = ma * att_r, tb = mb * att_r, tc2 = mc * att_r, td = md * att_r;
#pragma unroll
        for (int off = 1; off < 32; off <<= 1) {
          ta  += __shfl_xor(ta, off);
          tb  += __shfl_xor(tb, off);
          tc2 += __shfl_xor(tc2, off);
          td  += __shfl_xor(td, off);
        }
        float ga = __builtin_amdgcn_exp2f(ta);
        float gb = __builtin_amdgcn_exp2f(tb);
        float gc = __builtin_amdgcn_exp2f(tc2);
        float gd = __builtin_amdgcn_exp2f(td);
        num += ga * xa + gb * xb + gc * xc + gd * xd;
        den += ga + gb + gc + gd;
        efsum += fa + fb + fc + fd;
      }
      for (; i < cnt; ++i) {                   // <=3 unmasked tail edges
        int sa = __builtin_amdgcn_readlane(s_l, i);
        float xa = (xl + (size_t)sa * 64)[lane];
        const uint4* ep = ea_h + (size_t)(base + i) * 2;
        uint4 u0 = ep[0], u1 = ep[1];
        float fa = dot16h(u0, u1, wh);
        float ma = xa + xr_v + fa; ma = fmaxf(ma, NEG_SLOPE * ma);
        float ta = ma * att_r;
#pragma unroll
        for (int off = 1; off < 32; off <<= 1) ta += __shfl_xor(ta, off);
        float ga = __builtin_amdgcn_exp2f(ta);
        num += ga * xa;
        den += ga;
        efsum += fa;
      }
    }
    int deg = re - rs;
    float ef_self = efsum * __builtin_amdgcn_rcpf(fmaxf((float)deg, 1.f));
    float mm = xl_s + xr_v + ef_self;
    mm = fmaxf(mm, NEG_SLOPE * mm);
    float s2 = mm * att_r;
#pragma unroll
    for (int off = 1; off < 32; off <<= 1) s2 += __shfl_xor(s2, off);
    float e2 = __builtin_amdgcn_exp2f(s2);
    num += e2 * xl_s;
    den += e2;
    h[(size_t)n * 64 + lane] = fmaxf(num * __builtin_amdgcn_rcpf(fmaxf(den, 1e-16f)) + b_r, 0.f);
  }
}

// ------------------------------------------------- GAT layer2: half-wave per node (R12)
__global__ __launch_bounds__(256) void gat2_k(
    const int* __restrict__ rowptr, const int* __restrict__ csr_src,
    const uint4* __restrict__ ea_h, const float* __restrict__ we,
    const float* __restrict__ att, const float* __restrict__ b,
    const float* __restrict__ xl, const float* __restrict__ xr,
    float* __restrict__ h, int N) {
  int t = threadIdx.x;
  int lane = t & 63;
  int c = lane & 31;
  int half = lane >> 5;
  int hbase = lane & 32;
  h2v wh[8];
#pragma unroll
  for (int k = 0; k < 8; ++k) {
    wh[k].x = (_Float16)we[(2 * k) * 32 + c];
    wh[k].y = (_Float16)we[(2 * k + 1) * 32 + c];
  }
  float att_r = att[c] * LOG2E;
  float b_r = b[c];
  int wid = (blockIdx.x * blockDim.x + t) >> 6;
  int p0 = wid * 4;
  for (int jj = 0; jj < 4; ++jj) {
    int p = p0 + jj;
    if (p * 2 >= N) break;
    int n = p * 2 + half;
    if (n >= N) continue;
    float xr_v = xr[(size_t)n * 32 + c];
    float xl_s = xl[(size_t)n * 32 + c];
    float num = 0.f, den = 0.f, efsum = 0.f;
    int rs = rowptr[n], re = rowptr[n + 1];
    for (int base = rs; base < re; base += 32) {
      int cnt = min(32, re - base);
      int s_l = 0;
      if (c < cnt) s_l = csr_src[base + c];
      int i = 0;
      for (; i + 1 < cnt; i += 2) {
        int sa = __shfl(s_l, hbase + i), sb = __shfl(s_l, hbase + i + 1);
        float xa = xl[(size_t)sa * 32 + c];
        float xb = xl[(size_t)sb * 32 + c];
        const uint4* epa = ea_h + (size_t)(base + i) * 2;
        uint4 u0 = epa[0], u1 = epa[1], u2 = epa[2], u3 = epa[3];
        float fa = dot16h(u0, u1, wh);
        float fb = dot16h(u2, u3, wh);
        float ma = xa + xr_v + fa; ma = fmaxf(ma, NEG_SLOPE * ma);
        float mb = xb + xr_v + fb; mb = fmaxf(mb, NEG_SLOPE * mb);
        float ta = ma * att_r, tb = mb * att_r;
#pragma unroll
        for (int off = 1; off < 32; off <<= 1) {
          ta += __shfl_xor(ta, off);
          tb += __shfl_xor(tb, off);
        }
        float ga = __builtin_amdgcn_exp2f(ta), gb = __builtin_amdgcn_exp2f(tb);
        num += ga * xa + gb * xb;
        den += ga + gb;
        efsum += fa + fb;
      }
      if (i < cnt) {
        int sa = __shfl(s_l, hbase + i);
        float xa = xl[(size_t)sa * 32 + c];
        const uint4* epa = ea_h + (size_t)(base + i) * 2;
        uint4 u0 = epa[0], u1 = epa[1];
        float fa = dot16h(u0, u1, wh);
        float ma = xa + xr_v + fa; ma = fmaxf(ma, NEG_SLOPE * ma);
        float ta = ma * att_r;
#pragma unroll
        for (int off = 1; off < 32; off <<= 1) ta += __shfl_xor(ta, off);
        float ga = __builtin_amdgcn_exp2f(ta);
        num += ga * xa;
        den += ga;
        efsum += fa;
      }
    }
    int deg = re - rs;
    float ef_self = efsum * __builtin_amdgcn_rcpf(fmaxf((float)deg, 1.f));
    float mm = xl_s + xr_v + ef_self;
    mm = fmaxf(mm, NEG_SLOPE * mm);
    float s2 = mm * att_r;
#pragma unroll
    for (int off = 1; off < 32; off <<= 1) s2 += __shfl_xor(s2, off);
    float e2 = __builtin_amdgcn_exp2f(s2);
    num += e2 * xl_s;
    den += e2;
    h[(size_t)n * 32 + c] = fmaxf(num * __builtin_amdgcn_rcpf(fmaxf(den, 1e-16f)) + b_r, 0.f);
  }
}

// ------------------------------------------------- fused mean-pool + fc
__global__ __launch_bounds__(256) void pool_fc_k(
    const float* __restrict__ h, const int* __restrict__ batch,
    const float* __restrict__ wfc, const float* __restrict__ bfc,
    float* __restrict__ out, int N) {
  int g = blockIdx.x;
  __shared__ int srange[2];
  __shared__ float part[8][32];
  int t = threadIdx.x;
  if (t < 2) {
    int key = g + t;
    int lo = 0, hi = N;
    while (lo < hi) { int mid = (lo + hi) >> 1; if (batch[mid] < key) lo = mid + 1; else hi = mid; }
    srange[t] = lo;
  }
  __syncthreads();
  int rs = srange[0], re = srange[1];
  int c = t & 31, sub = t >> 5;
  float acc = 0.f;
  for (int n = rs + sub; n < re; n += 8) acc += h[(size_t)n * 32 + c];
  part[sub][c] = acc;
  __syncthreads();
  if (sub == 0) {
    float s = part[0][c];
#pragma unroll
    for (int i = 1; i < 8; ++i) s += part[i][c];
    part[0][c] = s / fmaxf((float)(re - rs), 1.f);
  }
  __syncthreads();
  if (sub == 0) {
    float a = 0.f;
#pragma unroll
    for (int k = 0; k < 32; ++k) a += part[0][k] * wfc[k * 32 + c];
    out[g * 32 + c] = a + bfc[c];
  }
}

// ----------------------------------------------------------------- launcher
extern "C" void kernel_launch(void* const* d_in, const int* in_sizes, int n_in,
                              void* d_out, int out_size, void* d_ws, size_t ws_size,
                              hipStream_t stream) {
  const float* x   = (const float*)d_in[0];
  const int*   ei  = (const int*)d_in[1];
  const float* ea  = (const float*)d_in[2];
  const int*   bat = (const int*)d_in[3];
  const float* wl1 = (const float*)d_in[4];
  const float* wr1 = (const float*)d_in[5];
  const float* we1 = (const float*)d_in[6];
  const float* at1 = (const float*)d_in[7];
  const float* b1  = (const float*)d_in[8];
  const float* wl2 = (const float*)d_in[9];
  const float* wr2 = (const float*)d_in[10];
  const float* we2 = (const float*)d_in[11];
  const float* at2 = (const float*)d_in[12];
  const float* b2  = (const float*)d_in[13];
  const float* wfc = (const float*)d_in[14];
  const float* bfc = (const float*)d_in[15];

  const int N = in_sizes[0] / 128;
  const int E = in_sizes[1] / 2;
  const int G = 256;
  const int* srcA = ei;
  const int* dstA = ei + E;

  // ---- workspace layout (~110 MB) ----
  uint4* ea_h   = (uint4*)d_ws;                      // E*2 uint4 (fp16 attrs)
  float* xl1    = (float*)(ea_h + (size_t)E * 2);    // N*64
  float* xr1    = xl1 + (size_t)N * 64;              // N*64
  int*   deg    = (int*)(xr1 + (size_t)N * 64);      // N
  int*   rowptr = deg + N;                           // N+1
  int*   cursor = rowptr + (N + 1);                  // N
  int*   aux    = cursor + N;                        // 512
  int*   csr_src= aux + 512;                         // E
  float* h1     = xr1;                               // in-place over xr1
  float* xl2    = xl1;                               // N*32
  float* xr2    = xl1 + (size_t)N * 32;              // N*32
  float* h2     = xr2;                               // in-place over xr2

  const int naux = (N + 255) / 256;
  const int ntiles1 = (N + 31) / 32;
  const int scatBlocks = (E + 255) / 256;

  // ---- CSR degree + scans ----
  (void)hipMemsetAsync(deg, 0, (size_t)N * sizeof(int), stream);
  deg_count_k<<<(E + 1023) / 1024, 256, 0, stream>>>(dstA, deg, E);
  scan1_k<<<naux, 256, 0, stream>>>(deg, rowptr, aux, N);
  scan2_k<<<1, 512, 0, stream>>>(aux, naux);
  scan3_k<<<(N + 256) / 256, 256, 0, stream>>>(rowptr, cursor, aux, N, E);

  // ---- transform1 ∥ scatter ----
  t1scat_k<<<ntiles1 + scatBlocks, 256, 0, stream>>>(x, wl1, wr1, xl1, xr1, N, ntiles1,
                                                     srcA, dstA, ea, cursor,
                                                     csr_src, ea_h, E);

  // ---- layer 1 ----
  {
    int blocks1 = (N + 15) / 16;
    gat1_k<<<blocks1, 256, 0, stream>>>(rowptr, csr_src, ea_h, we1, at1, b1,
                                        xl1, xr1, h1, N);
  }

  // ---- layer 2 ----
  transform2_k<<<(N + 63) / 64, 256, 0, stream>>>(h1, wl2, wr2, xl2, xr2, N);
  {
    int P = (N + 1) / 2;
    int blocks2 = (P + 15) / 16;
    gat2_k<<<blocks2, 256, 0, stream>>>(rowptr, csr_src, ea_h, we2, at2, b2,
                                        xl2, xr2, h2, N);
  }

  // ---- fused pool + fc ----
  pool_fc_k<<<G, 256, 0, stream>>>(h2, bat, wfc, bfc, (float*)d_out, N);
}